// Round 2
// baseline (902.194 us; speedup 1.0000x reference)
//
#include <hip/hip_runtime.h>
#include <stdint.h>

#define NN 100000
#define NE 1600000
#define ET (NE + NN)
#define HC 128
#define HID 64
#define NCLS 12

// ---------- CSR build ----------
__global__ void k_zero(int* p, int n) {
    int i = blockIdx.x * 256 + threadIdx.x;
    if (i < n) p[i] = 0;
}

__global__ void k_count(const int* __restrict__ ei, int* __restrict__ cnt) {
    int i = blockIdx.x * 256 + threadIdx.x;
    if (i >= ET) return;
    int d = (i < NE) ? ei[NE + i] : (i - NE);
    atomicAdd(&cnt[d], 1);
}

__global__ void k_scan1(const int* __restrict__ cnt, int* __restrict__ rp, int* __restrict__ bsum) {
    __shared__ int s[256];
    int tid = threadIdx.x;
    int i = blockIdx.x * 256 + tid;
    int v = (i < NN) ? cnt[i] : 0;
    s[tid] = v;
    __syncthreads();
    for (int o = 1; o < 256; o <<= 1) {
        int t = (tid >= o) ? s[tid - o] : 0;
        __syncthreads();
        s[tid] += t;
        __syncthreads();
    }
    if (i < NN) rp[i + 1] = s[tid];
    if (tid == 255) bsum[blockIdx.x] = s[255];
}

__global__ void k_scan2(int* __restrict__ bsum, int nb) {
    __shared__ int s[512];
    int tid = threadIdx.x;
    int v = (tid < nb) ? bsum[tid] : 0;
    s[tid] = v;
    __syncthreads();
    for (int o = 1; o < 512; o <<= 1) {
        int t = (tid >= o) ? s[tid - o] : 0;
        __syncthreads();
        s[tid] += t;
        __syncthreads();
    }
    if (tid < nb) bsum[tid] = s[tid] - v;  // exclusive
}

__global__ void k_scan3(int* __restrict__ rp, const int* __restrict__ bsum) {
    int i = blockIdx.x * 256 + threadIdx.x;
    if (i >= NN) return;
    rp[i + 1] += bsum[i >> 8];
    if (i == 0) rp[0] = 0;
}

__global__ void k_scatter(const int* __restrict__ ei, const int* __restrict__ rp,
                          int* __restrict__ fill, int* __restrict__ colx) {
    int i = blockIdx.x * 256 + threadIdx.x;
    if (i >= ET) return;
    int s, d;
    if (i < NE) { s = ei[i]; d = ei[NE + i]; } else { s = d = i - NE; }
    int pos = rp[d] + atomicAdd(&fill[d], 1);
    colx[pos] = s;
}

// ---------- GEMM: out[NN,128] = in[NN,K] @ W[K,128], all f32, K-tiled at 64 ----------
template <int K>
__global__ __launch_bounds__(256) void k_gemm(const float* __restrict__ xg,
                                              const float* __restrict__ Wg,
                                              float* __restrict__ outp) {
    constexpr int KT = (K < 64) ? K : 64;
    __shared__ __align__(16) float sIn[64 * KT];
    __shared__ __align__(16) float sW[KT * HC];
    int tid = threadIdx.x;
    long n0 = (long)blockIdx.x * 64;
    int cg = tid & 31, ng = tid >> 5;
    float4 acc[8];
#pragma unroll
    for (int i = 0; i < 8; i++) acc[i] = make_float4(0.f, 0.f, 0.f, 0.f);

    for (int kt = 0; kt < K; kt += KT) {
        // stage W rows kt..kt+KT-1 (float4)
        const float4* wsrc = (const float4*)(Wg + (long)kt * HC);
        for (int c = tid; c < KT * HC / 4; c += 256) ((float4*)sW)[c] = wsrc[c];
        // stage 64 input rows x KT cols (float4)
        for (int c = tid; c < 64 * KT / 4; c += 256) {
            int n = c / (KT / 4), kc = c % (KT / 4);
            long gn = n0 + n;
            float4 v = make_float4(0.f, 0.f, 0.f, 0.f);
            if (gn < NN) v = *(const float4*)(xg + gn * K + kt + kc * 4);
            *(float4*)(sIn + n * KT + kc * 4) = v;
        }
        __syncthreads();
        for (int k = 0; k < KT; ++k) {
            float4 w = *(const float4*)(sW + k * HC + cg * 4);
#pragma unroll
            for (int i = 0; i < 8; i++) {
                float a = sIn[(ng * 8 + i) * KT + k];
                acc[i].x = fmaf(a, w.x, acc[i].x);
                acc[i].y = fmaf(a, w.y, acc[i].y);
                acc[i].z = fmaf(a, w.z, acc[i].z);
                acc[i].w = fmaf(a, w.w, acc[i].w);
            }
        }
        __syncthreads();
    }
#pragma unroll
    for (int i = 0; i < 8; i++) {
        long n = n0 + ng * 8 + i;
        if (n < NN) *(float4*)(outp + n * HC + cg * 4) = acc[i];
    }
}

// ---------- attention projections: als/ald [NN*2] f32 ----------
__global__ __launch_bounds__(256) void k_proj(const float* __restrict__ h,
                                              const float* __restrict__ avs,
                                              const float* __restrict__ avd,
                                              float* __restrict__ als, float* __restrict__ ald) {
    __shared__ float ss[HC], sd[HC];
    int tid = threadIdx.x;
    if (tid < HC) { ss[tid] = avs[tid]; sd[tid] = avd[tid]; }
    __syncthreads();
    int t = blockIdx.x * 256 + tid;
    if (t >= NN * 2) return;
    int n = t >> 1, hd = t & 1;
    const float* row = h + (long)n * HC + hd * HID;
    const float* av = ss + hd * HID;
    const float* dv = sd + hd * HID;
    float s_ = 0.f, d_ = 0.f;
#pragma unroll 16
    for (int c = 0; c < HID; c++) {
        float v = row[c];
        s_ = fmaf(v, av[c], s_);
        d_ = fmaf(v, dv[c], d_);
    }
    als[t] = s_;
    ald[t] = d_;
}

// ---------- aggregation: wave per dst node; fused softmax + weighted sum + bias + prelu ----------
template <int MEAN>
__global__ __launch_bounds__(256) void k_agg(const int* __restrict__ rp, const int* __restrict__ colx,
                                             const float* __restrict__ h,
                                             const float* __restrict__ als, const float* __restrict__ ald,
                                             const float* __restrict__ bias,
                                             const float* __restrict__ pap,
                                             float* __restrict__ outp) {
    int wid = blockIdx.x * (blockDim.x >> 6) + (threadIdx.x >> 6);
    if (wid >= NN) return;
    int lane = threadIdx.x & 63;
    int start = rp[wid], end = rp[wid + 1];
    int deg = end - start;
    float2 adv = *(const float2*)(ald + 2 * wid);

    // pass 1: segment max (lanes parallel over neighbors); cache first-64 cols in regs
    int cs = (start + lane < end) ? colx[start + lane] : 0;
    float m0 = -1e30f, m1 = -1e30f;
    for (int j = start + lane; j < end; j += 64) {
        int s = (j == start + lane) ? cs : colx[j];
        float2 asv = *(const float2*)(als + 2 * s);
        float e0 = asv.x + adv.x, e1 = asv.y + adv.y;
        e0 = e0 >= 0.f ? e0 : 0.2f * e0;
        e1 = e1 >= 0.f ? e1 : 0.2f * e1;
        m0 = fmaxf(m0, e0);
        m1 = fmaxf(m1, e1);
    }
#pragma unroll
    for (int o = 32; o; o >>= 1) {
        m0 = fmaxf(m0, __shfl_xor(m0, o));
        m1 = fmaxf(m1, __shfl_xor(m1, o));
    }

    // pass 2: out = sum(exp(e-m) * h[src]) / sum(exp(e-m)); lane holds channels 2l,2l+1
    bool hi_ = lane >= 32;
    float den0 = 0.f, den1 = 0.f, ax = 0.f, ay = 0.f;
    for (int jj = 0; jj < deg; ++jj) {
        int s = (jj < 64) ? __shfl(cs, jj) : colx[start + jj];
        float2 asv = *(const float2*)(als + 2 * s);
        float e0 = asv.x + adv.x, e1 = asv.y + adv.y;
        e0 = e0 >= 0.f ? e0 : 0.2f * e0;
        e1 = e1 >= 0.f ? e1 : 0.2f * e1;
        float w0 = __expf(e0 - m0), w1 = __expf(e1 - m1);
        den0 += w0;
        den1 += w1;
        float2 hv = *(const float2*)(h + (long)s * HC + lane * 2);
        float w = hi_ ? w1 : w0;
        ax = fmaf(w, hv.x, ax);
        ay = fmaf(w, hv.y, ay);
    }
    float inv = 1.0f / (hi_ ? den1 : den0);
    float pa = pap[0];
    if (!MEAN) {
        float2 bu = *(const float2*)(bias + lane * 2);
        float o0 = ax * inv + bu.x;
        float o1 = ay * inv + bu.y;
        o0 = o0 >= 0.f ? o0 : pa * o0;
        o1 = o1 >= 0.f ? o1 : pa * o1;
        *(float2*)(outp + (long)wid * HC + lane * 2) = make_float2(o0, o1);
    } else {
        float v0 = ax * inv, v1 = ay * inv;
        float p0 = __shfl_xor(v0, 32), p1 = __shfl_xor(v1, 32);
        if (lane < 32) {
            float2 bu = *(const float2*)(bias + lane * 2);
            float o0 = 0.5f * (v0 + p0) + bu.x;
            float o1 = 0.5f * (v1 + p1) + bu.y;
            o0 = o0 >= 0.f ? o0 : pa * o0;
            o1 = o1 >= 0.f ? o1 : pa * o1;
            *(float2*)(outp + (long)wid * HID + lane * 2) = make_float2(o0, o1);
        }
    }
}

// ---------- classifier: out = hin @ Wc + bc ----------
__global__ __launch_bounds__(256) void k_cls(const float* __restrict__ hin,
                                             const float* __restrict__ Wc,
                                             const float* __restrict__ bcp,
                                             float* __restrict__ outp) {
    __shared__ float sW[HID * NCLS];
    __shared__ float sb[NCLS];
    int tid = threadIdx.x;
    for (int c = tid; c < HID * NCLS; c += 256) sW[c] = Wc[c];
    if (tid < NCLS) sb[tid] = bcp[tid];
    __syncthreads();
    int n = blockIdx.x * 256 + tid;
    if (n >= NN) return;
    float o[NCLS];
#pragma unroll
    for (int k = 0; k < NCLS; k++) o[k] = sb[k];
    const float* row = hin + (long)n * HID;
#pragma unroll 8
    for (int c = 0; c < HID; c++) {
        float v = row[c];
#pragma unroll
        for (int k = 0; k < NCLS; k++) o[k] = fmaf(v, sW[c * NCLS + k], o[k]);
    }
#pragma unroll
    for (int k = 0; k < NCLS; k += 2)
        *(float2*)(outp + (long)n * NCLS + k) = make_float2(o[k], o[k + 1]);
}

extern "C" void kernel_launch(void* const* d_in, const int* in_sizes, int n_in,
                              void* d_out, int out_size, void* d_ws, size_t ws_size,
                              hipStream_t stream) {
    const float* x   = (const float*)d_in[0];
    const int*   ei  = (const int*)d_in[1];
    const float* W1  = (const float*)d_in[2];
    const float* a1s = (const float*)d_in[3];
    const float* a1d = (const float*)d_in[4];
    const float* b1  = (const float*)d_in[5];
    const float* W2  = (const float*)d_in[6];
    const float* a2s = (const float*)d_in[7];
    const float* a2d = (const float*)d_in[8];
    const float* b2  = (const float*)d_in[9];
    const float* W3  = (const float*)d_in[10];
    const float* a3s = (const float*)d_in[11];
    const float* a3d = (const float*)d_in[12];
    const float* b3  = (const float*)d_in[13];
    const float* pa  = (const float*)d_in[14];
    const float* Wc  = (const float*)d_in[15];
    const float* bc  = (const float*)d_in[16];
    float* out = (float*)d_out;

    char* w = (char*)d_ws;
    size_t off = 0;
    auto take = [&](size_t b) { void* p = w + off; off += (b + 255) & ~(size_t)255; return p; };
    int* cnt    = (int*)take((size_t)NN * 4);
    int* rp     = (int*)take((size_t)(NN + 1) * 4);
    int* bsum   = (int*)take(2048);
    int* colx   = (int*)take((size_t)ET * 4);
    float* als  = (float*)take((size_t)NN * 8);
    float* ald  = (float*)take((size_t)NN * 8);
    float* bufA = (float*)take((size_t)NN * HC * 4);
    float* bufB = (float*)take((size_t)NN * HC * 4);

    int nb = (NN + 255) / 256;      // 391
    int eb = (ET + 255) / 256;
    int gb = (NN + 63) / 64;        // 1563
    int ab = (NN + 3) / 4;          // 25000
    int pb = (NN * 2 + 255) / 256;

    // CSR build (reused by all 3 layers)
    k_zero<<<nb, 256, 0, stream>>>(cnt, NN);
    k_count<<<eb, 256, 0, stream>>>(ei, cnt);
    k_scan1<<<nb, 256, 0, stream>>>(cnt, rp, bsum);
    k_scan2<<<1, 512, 0, stream>>>(bsum, nb);
    k_scan3<<<nb, 256, 0, stream>>>(rp, bsum);
    k_zero<<<nb, 256, 0, stream>>>(cnt, NN);
    k_scatter<<<eb, 256, 0, stream>>>(ei, rp, cnt, colx);

    // layer 1
    k_gemm<32><<<gb, 256, 0, stream>>>(x, W1, bufA);
    k_proj<<<pb, 256, 0, stream>>>(bufA, a1s, a1d, als, ald);
    k_agg<0><<<ab, 256, 0, stream>>>(rp, colx, bufA, als, ald, b1, pa, bufB);
    // layer 2
    k_gemm<128><<<gb, 256, 0, stream>>>(bufB, W2, bufA);
    k_proj<<<pb, 256, 0, stream>>>(bufA, a2s, a2d, als, ald);
    k_agg<0><<<ab, 256, 0, stream>>>(rp, colx, bufA, als, ald, b2, pa, bufB);
    // layer 3 (head mean)
    k_gemm<128><<<gb, 256, 0, stream>>>(bufB, W3, bufA);
    k_proj<<<pb, 256, 0, stream>>>(bufA, a3s, a3d, als, ald);
    k_agg<1><<<ab, 256, 0, stream>>>(rp, colx, bufA, als, ald, b3, pa, bufB);
    // classifier
    k_cls<<<nb, 256, 0, stream>>>(bufB, Wc, bc, out);
}

// Round 3
// 825.664 us; speedup vs baseline: 1.0927x; 1.0927x over previous
//
#include <hip/hip_runtime.h>
#include <stdint.h>

#define NN 100000
#define NE 1600000
#define ET (NE + NN)
#define HC 128
#define HID 64
#define NCLS 12
#define CAP 256

// ---------- CSR build ----------
__global__ void k_zero(int* p, int n) {
    int i = blockIdx.x * 256 + threadIdx.x;
    if (i < n) p[i] = 0;
}

__global__ void k_count(const int* __restrict__ ei, int* __restrict__ cnt) {
    int i = blockIdx.x * 256 + threadIdx.x;
    if (i >= ET) return;
    int d = (i < NE) ? ei[NE + i] : (i - NE);
    atomicAdd(&cnt[d], 1);
}

__global__ void k_scan1(const int* __restrict__ cnt, int* __restrict__ rp, int* __restrict__ bsum) {
    __shared__ int s[256];
    int tid = threadIdx.x;
    int i = blockIdx.x * 256 + tid;
    int v = (i < NN) ? cnt[i] : 0;
    s[tid] = v;
    __syncthreads();
    for (int o = 1; o < 256; o <<= 1) {
        int t = (tid >= o) ? s[tid - o] : 0;
        __syncthreads();
        s[tid] += t;
        __syncthreads();
    }
    if (i < NN) rp[i + 1] = s[tid];
    if (tid == 255) bsum[blockIdx.x] = s[255];
}

__global__ void k_scan2(int* __restrict__ bsum, int nb) {
    __shared__ int s[512];
    int tid = threadIdx.x;
    int v = (tid < nb) ? bsum[tid] : 0;
    s[tid] = v;
    __syncthreads();
    for (int o = 1; o < 512; o <<= 1) {
        int t = (tid >= o) ? s[tid - o] : 0;
        __syncthreads();
        s[tid] += t;
        __syncthreads();
    }
    if (tid < nb) bsum[tid] = s[tid] - v;  // exclusive
}

__global__ void k_scan3(int* __restrict__ rp, const int* __restrict__ bsum) {
    int i = blockIdx.x * 256 + threadIdx.x;
    if (i >= NN) return;
    rp[i + 1] += bsum[i >> 8];
    if (i == 0) rp[0] = 0;
}

__global__ void k_scatter(const int* __restrict__ ei, const int* __restrict__ rp,
                          int* __restrict__ fill, int* __restrict__ colx) {
    int i = blockIdx.x * 256 + threadIdx.x;
    if (i >= ET) return;
    int s, d;
    if (i < NE) { s = ei[i]; d = ei[NE + i]; } else { s = d = i - NE; }
    int pos = rp[d] + atomicAdd(&fill[d], 1);
    colx[pos] = s;
}

// ---------- layer-1 projected attention vectors: pv[sd][h][32] ----------
__global__ void k_avec(const float* __restrict__ W1, const float* __restrict__ a1s,
                       const float* __restrict__ a1d, float* __restrict__ pv) {
    int t = threadIdx.x;  // 128 threads
    int sd = t >> 6, h = (t >> 5) & 1, f = t & 31;
    const float* a = sd ? a1d : a1s;
    float acc = 0.f;
    for (int c = 0; c < 64; c++) acc = fmaf(W1[f * HC + h * 64 + c], a[h * 64 + c], acc);
    pv[t] = acc;
}

// ---------- layer-1 logits from x: als/ald[2n+h] = x[n]·pv[h] ----------
__global__ __launch_bounds__(256) void k_att1(const float* __restrict__ x,
                                              const float* __restrict__ pv,
                                              float* __restrict__ als, float* __restrict__ ald) {
    __shared__ float sIn[128 * 33];
    __shared__ float spv[128];
    int t = threadIdx.x;
    long n0 = (long)blockIdx.x * 128;
    if (t < 128) spv[t] = pv[t];
    for (int c = t; c < 128 * 8; c += 256) {
        int row = c >> 3, col = (c & 7) * 4;
        long gn = n0 + row;
        float4 v = make_float4(0.f, 0.f, 0.f, 0.f);
        if (gn < NN) v = *(const float4*)(x + gn * 32 + col);
        float* dst = &sIn[row * 33 + col];
        dst[0] = v.x; dst[1] = v.y; dst[2] = v.z; dst[3] = v.w;
    }
    __syncthreads();
    int n = t >> 1, h = t & 1;
    long gn = n0 + n;
    if (gn >= NN) return;
    const float* row = &sIn[n * 33];
    const float* as_ = &spv[h * 32];
    const float* ad_ = &spv[64 + h * 32];
    float s_ = 0.f, d_ = 0.f;
#pragma unroll
    for (int f = 0; f < 32; f++) {
        float v = row[f];
        s_ = fmaf(v, as_[f], s_);
        d_ = fmaf(v, ad_[f], d_);
    }
    als[2 * gn + h] = s_;
    ald[2 * gn + h] = d_;
}

// ---------- layer-1 aggregation: gather x (32ch), out xbar[N][2][32] ----------
__global__ __launch_bounds__(256) void k_aggx(const int* __restrict__ rp, const int* __restrict__ colx,
                                              const float* __restrict__ x,
                                              const float* __restrict__ als, const float* __restrict__ ald,
                                              float* __restrict__ xbar) {
    __shared__ float4 sE[4][CAP];
    int wv = threadIdx.x >> 6, lane = threadIdx.x & 63;
    int wid = blockIdx.x * 4 + wv;
    int start = rp[wid], end = rp[wid + 1], deg = end - start;
    float2 adv = *(const float2*)(ald + 2 * wid);
    float den0 = 0.f, den1 = 0.f;
    for (int j = start + lane; j < end; j += 64) {
        int s = colx[j];
        float2 asv = *(const float2*)(als + 2 * s);
        float e0 = asv.x + adv.x, e1 = asv.y + adv.y;
        e0 = fmaxf(e0, 0.2f * e0);
        e1 = fmaxf(e1, 0.2f * e1);
        float w0 = __expf(e0), w1 = __expf(e1);
        den0 += w0; den1 += w1;
        int idx = j - start;
        if (idx < CAP) {
            float4 e; e.x = __int_as_float(s); e.y = w0; e.z = w1; e.w = 0.f;
            sE[wv][idx] = e;
        }
    }
#pragma unroll
    for (int o = 32; o; o >>= 1) { den0 += __shfl_xor(den0, o); den1 += __shfl_xor(den1, o); }
    __syncthreads();
    int ch = lane & 31;
    bool hi_ = lane >= 32;
    float acc = 0.f;
    int nfast = deg < CAP ? deg : CAP;
#pragma unroll 2
    for (int jj = 0; jj < nfast; ++jj) {
        float4 e = sE[wv][jj];
        int s = __builtin_amdgcn_readfirstlane(__float_as_int(e.x));
        float w = hi_ ? e.z : e.y;
        acc = fmaf(w, x[(long)s * 32 + ch], acc);
    }
    for (int jj = CAP; jj < deg; ++jj) {  // overflow fallback (rare/never)
        int s = colx[start + jj];
        float2 asv = *(const float2*)(als + 2 * s);
        float e0 = asv.x + adv.x, e1 = asv.y + adv.y;
        e0 = fmaxf(e0, 0.2f * e0);
        e1 = fmaxf(e1, 0.2f * e1);
        float w = hi_ ? __expf(e1) : __expf(e0);
        acc = fmaf(w, x[(long)s * 32 + ch], acc);
    }
    acc *= 1.0f / (hi_ ? den1 : den0);
    xbar[(long)wid * 64 + lane] = acc;
}

// ---------- layer-1 post GEMM (block-diag K=32/head) + bias + prelu ----------
__global__ __launch_bounds__(256) void k_post1(const float* __restrict__ xb,
                                               const float* __restrict__ W1,
                                               const float* __restrict__ b1,
                                               const float* __restrict__ pap,
                                               float* __restrict__ outp) {
    __shared__ __align__(16) float sIn[64 * 64];
    __shared__ __align__(16) float sW[32 * HC];
    __shared__ float sB[HC];
    int tid = threadIdx.x;
    long n0 = (long)blockIdx.x * 64;
    for (int c = tid; c < 64 * 16; c += 256) {
        int row = c >> 4, col = (c & 15) * 4;
        long gn = n0 + row;
        float4 v = make_float4(0.f, 0.f, 0.f, 0.f);
        if (gn < NN) v = *(const float4*)(xb + gn * 64 + col);
        *(float4*)(sIn + row * 64 + col) = v;
    }
    for (int c = tid; c < 32 * HC / 4; c += 256) ((float4*)sW)[c] = ((const float4*)W1)[c];
    if (tid < HC) sB[tid] = b1[tid];
    __syncthreads();
    int cg = tid & 31, ng = tid >> 5, head = cg >> 4;
    float4 acc[8];
#pragma unroll
    for (int i = 0; i < 8; i++) acc[i] = make_float4(0.f, 0.f, 0.f, 0.f);
    for (int k = 0; k < 32; k++) {
        float4 w = *(const float4*)(sW + k * HC + cg * 4);
#pragma unroll
        for (int i = 0; i < 8; i++) {
            float a = sIn[(ng * 8 + i) * 64 + head * 32 + k];
            acc[i].x = fmaf(a, w.x, acc[i].x);
            acc[i].y = fmaf(a, w.y, acc[i].y);
            acc[i].z = fmaf(a, w.z, acc[i].z);
            acc[i].w = fmaf(a, w.w, acc[i].w);
        }
    }
    float pa = pap[0];
    float4 b = *(const float4*)(sB + cg * 4);
#pragma unroll
    for (int i = 0; i < 8; i++) {
        long n = n0 + ng * 8 + i;
        if (n < NN) {
            float4 o;
            o.x = acc[i].x + b.x; o.y = acc[i].y + b.y;
            o.z = acc[i].z + b.z; o.w = acc[i].w + b.w;
            o.x = o.x >= 0.f ? o.x : pa * o.x;
            o.y = o.y >= 0.f ? o.y : pa * o.y;
            o.z = o.z >= 0.f ? o.z : pa * o.z;
            o.w = o.w >= 0.f ? o.w : pa * o.w;
            *(float4*)(outp + n * HC + cg * 4) = o;
        }
    }
}

// ---------- GEMM h = in @ W (K=128) + fused attention projections ----------
__global__ __launch_bounds__(256) void k_gemm(const float* __restrict__ xg,
                                              const float* __restrict__ Wg,
                                              const float* __restrict__ avs,
                                              const float* __restrict__ avd,
                                              float* __restrict__ outp,
                                              float* __restrict__ als, float* __restrict__ ald) {
    constexpr int K = 128, KT = 64;
    __shared__ __align__(16) float sIn[64 * KT];
    __shared__ __align__(16) float sW[KT * HC];
    __shared__ float sas[HC], sad[HC];
    int tid = threadIdx.x;
    long n0 = (long)blockIdx.x * 64;
    if (tid < HC) { sas[tid] = avs[tid]; sad[tid] = avd[tid]; }
    int cg = tid & 31, ng = tid >> 5;
    float4 acc[8];
#pragma unroll
    for (int i = 0; i < 8; i++) acc[i] = make_float4(0.f, 0.f, 0.f, 0.f);

    for (int kt = 0; kt < K; kt += KT) {
        __syncthreads();
        const float4* wsrc = (const float4*)(Wg + (long)kt * HC);
        for (int c = tid; c < KT * HC / 4; c += 256) ((float4*)sW)[c] = wsrc[c];
        for (int c = tid; c < 64 * KT / 4; c += 256) {
            int row = c / (KT / 4), kc = c % (KT / 4);
            long gn = n0 + row;
            float4 v = make_float4(0.f, 0.f, 0.f, 0.f);
            if (gn < NN) v = *(const float4*)(xg + gn * K + kt + kc * 4);
            *(float4*)(sIn + row * KT + kc * 4) = v;
        }
        __syncthreads();
        for (int k = 0; k < KT; k += 4) {
            float4 w0 = *(const float4*)(sW + (k + 0) * HC + cg * 4);
            float4 w1 = *(const float4*)(sW + (k + 1) * HC + cg * 4);
            float4 w2 = *(const float4*)(sW + (k + 2) * HC + cg * 4);
            float4 w3 = *(const float4*)(sW + (k + 3) * HC + cg * 4);
#pragma unroll
            for (int i = 0; i < 8; i++) {
                float4 a = *(const float4*)(sIn + (ng * 8 + i) * KT + k);
                acc[i].x = fmaf(a.x, w0.x, acc[i].x); acc[i].y = fmaf(a.x, w0.y, acc[i].y);
                acc[i].z = fmaf(a.x, w0.z, acc[i].z); acc[i].w = fmaf(a.x, w0.w, acc[i].w);
                acc[i].x = fmaf(a.y, w1.x, acc[i].x); acc[i].y = fmaf(a.y, w1.y, acc[i].y);
                acc[i].z = fmaf(a.y, w1.z, acc[i].z); acc[i].w = fmaf(a.y, w1.w, acc[i].w);
                acc[i].x = fmaf(a.z, w2.x, acc[i].x); acc[i].y = fmaf(a.z, w2.y, acc[i].y);
                acc[i].z = fmaf(a.z, w2.z, acc[i].z); acc[i].w = fmaf(a.z, w2.w, acc[i].w);
                acc[i].x = fmaf(a.w, w3.x, acc[i].x); acc[i].y = fmaf(a.w, w3.y, acc[i].y);
                acc[i].z = fmaf(a.w, w3.z, acc[i].z); acc[i].w = fmaf(a.w, w3.w, acc[i].w);
            }
        }
    }
    int head = cg >> 4;
#pragma unroll
    for (int i = 0; i < 8; i++) {
        long n = n0 + ng * 8 + i;
        if (n < NN) *(float4*)(outp + n * HC + cg * 4) = acc[i];
        // fused proj: reduce acc·a over this head's 16-lane column group
        const float* ap = (const float*)&acc[i];
        float s_ = 0.f, d_ = 0.f;
#pragma unroll
        for (int j = 0; j < 4; j++) {
            int c = cg * 4 + j;
            s_ = fmaf(ap[j], sas[c], s_);
            d_ = fmaf(ap[j], sad[c], d_);
        }
#pragma unroll
        for (int o = 8; o; o >>= 1) { s_ += __shfl_xor(s_, o); d_ += __shfl_xor(d_, o); }
        if ((cg & 15) == 0 && n < NN) {
            als[2 * n + head] = s_;
            ald[2 * n + head] = d_;
        }
    }
}

// ---------- aggregation over h (128ch): single-pass, LDS-cached weights ----------
template <int MEAN>
__global__ __launch_bounds__(256) void k_agg(const int* __restrict__ rp, const int* __restrict__ colx,
                                             const float* __restrict__ h,
                                             const float* __restrict__ als, const float* __restrict__ ald,
                                             const float* __restrict__ bias,
                                             const float* __restrict__ pap,
                                             float* __restrict__ outp) {
    __shared__ float4 sE[4][CAP];
    int wv = threadIdx.x >> 6, lane = threadIdx.x & 63;
    int wid = blockIdx.x * 4 + wv;
    int start = rp[wid], end = rp[wid + 1], deg = end - start;
    float2 adv = *(const float2*)(ald + 2 * wid);
    float den0 = 0.f, den1 = 0.f;
    for (int j = start + lane; j < end; j += 64) {
        int s = colx[j];
        float2 asv = *(const float2*)(als + 2 * s);
        float e0 = asv.x + adv.x, e1 = asv.y + adv.y;
        e0 = fmaxf(e0, 0.2f * e0);
        e1 = fmaxf(e1, 0.2f * e1);
        float w0 = __expf(e0), w1 = __expf(e1);
        den0 += w0; den1 += w1;
        int idx = j - start;
        if (idx < CAP) {
            float4 e; e.x = __int_as_float(s); e.y = w0; e.z = w1; e.w = 0.f;
            sE[wv][idx] = e;
        }
    }
#pragma unroll
    for (int o = 32; o; o >>= 1) { den0 += __shfl_xor(den0, o); den1 += __shfl_xor(den1, o); }
    __syncthreads();
    bool hi_ = lane >= 32;
    float ax = 0.f, ay = 0.f;
    int nfast = deg < CAP ? deg : CAP;
#pragma unroll 2
    for (int jj = 0; jj < nfast; ++jj) {
        float4 e = sE[wv][jj];
        int s = __builtin_amdgcn_readfirstlane(__float_as_int(e.x));
        float w = hi_ ? e.z : e.y;
        float2 hv = *(const float2*)(h + (long)s * HC + lane * 2);
        ax = fmaf(w, hv.x, ax);
        ay = fmaf(w, hv.y, ay);
    }
    for (int jj = CAP; jj < deg; ++jj) {  // overflow fallback (rare/never)
        int s = colx[start + jj];
        float2 asv = *(const float2*)(als + 2 * s);
        float e0 = asv.x + adv.x, e1 = asv.y + adv.y;
        e0 = fmaxf(e0, 0.2f * e0);
        e1 = fmaxf(e1, 0.2f * e1);
        float w = hi_ ? __expf(e1) : __expf(e0);
        float2 hv = *(const float2*)(h + (long)s * HC + lane * 2);
        ax = fmaf(w, hv.x, ax);
        ay = fmaf(w, hv.y, ay);
    }
    float inv = 1.0f / (hi_ ? den1 : den0);
    float pa = pap[0];
    if (!MEAN) {
        float2 bu = *(const float2*)(bias + lane * 2);
        float o0 = ax * inv + bu.x;
        float o1 = ay * inv + bu.y;
        o0 = o0 >= 0.f ? o0 : pa * o0;
        o1 = o1 >= 0.f ? o1 : pa * o1;
        *(float2*)(outp + (long)wid * HC + lane * 2) = make_float2(o0, o1);
    } else {
        float v0 = ax * inv, v1 = ay * inv;
        float p0 = __shfl_xor(v0, 32), p1 = __shfl_xor(v1, 32);
        if (lane < 32) {
            float2 bu = *(const float2*)(bias + lane * 2);
            float o0 = 0.5f * (v0 + p0) + bu.x;
            float o1 = 0.5f * (v1 + p1) + bu.y;
            o0 = o0 >= 0.f ? o0 : pa * o0;
            o1 = o1 >= 0.f ? o1 : pa * o1;
            *(float2*)(outp + (long)wid * HID + lane * 2) = make_float2(o0, o1);
        }
    }
}

// ---------- classifier ----------
__global__ __launch_bounds__(256) void k_cls(const float* __restrict__ hin,
                                             const float* __restrict__ Wc,
                                             const float* __restrict__ bcp,
                                             float* __restrict__ outp) {
    __shared__ float sW[HID * NCLS];
    __shared__ float sb[NCLS];
    int tid = threadIdx.x;
    for (int c = tid; c < HID * NCLS; c += 256) sW[c] = Wc[c];
    if (tid < NCLS) sb[tid] = bcp[tid];
    __syncthreads();
    int n = blockIdx.x * 256 + tid;
    if (n >= NN) return;
    float o[NCLS];
#pragma unroll
    for (int k = 0; k < NCLS; k++) o[k] = sb[k];
    const float* row = hin + (long)n * HID;
#pragma unroll 8
    for (int c = 0; c < HID; c++) {
        float v = row[c];
#pragma unroll
        for (int k = 0; k < NCLS; k++) o[k] = fmaf(v, sW[c * NCLS + k], o[k]);
    }
#pragma unroll
    for (int k = 0; k < NCLS; k += 2)
        *(float2*)(outp + (long)n * NCLS + k) = make_float2(o[k], o[k + 1]);
}

extern "C" void kernel_launch(void* const* d_in, const int* in_sizes, int n_in,
                              void* d_out, int out_size, void* d_ws, size_t ws_size,
                              hipStream_t stream) {
    const float* x   = (const float*)d_in[0];
    const int*   ei  = (const int*)d_in[1];
    const float* W1  = (const float*)d_in[2];
    const float* a1s = (const float*)d_in[3];
    const float* a1d = (const float*)d_in[4];
    const float* b1  = (const float*)d_in[5];
    const float* W2  = (const float*)d_in[6];
    const float* a2s = (const float*)d_in[7];
    const float* a2d = (const float*)d_in[8];
    const float* b2  = (const float*)d_in[9];
    const float* W3  = (const float*)d_in[10];
    const float* a3s = (const float*)d_in[11];
    const float* a3d = (const float*)d_in[12];
    const float* b3  = (const float*)d_in[13];
    const float* pa  = (const float*)d_in[14];
    const float* Wc  = (const float*)d_in[15];
    const float* bc  = (const float*)d_in[16];
    float* out = (float*)d_out;

    char* w = (char*)d_ws;
    size_t off = 0;
    auto take = [&](size_t b) { void* p = w + off; off += (b + 255) & ~(size_t)255; return p; };
    int* cnt    = (int*)take((size_t)NN * 4);
    int* rp     = (int*)take((size_t)(NN + 1) * 4);
    int* bsum   = (int*)take(2048);
    int* colx   = (int*)take((size_t)ET * 4);
    float* als  = (float*)take((size_t)NN * 8);
    float* ald  = (float*)take((size_t)NN * 8);
    float* pv   = (float*)take(512);
    float* bufA = (float*)take((size_t)NN * HC * 4);   // also holds xbar [N,64]
    float* bufB = (float*)take((size_t)NN * HC * 4);
    float* xbar = bufA;

    int nb = (NN + 255) / 256;       // 391
    int eb = (ET + 255) / 256;
    int gb = (NN + 63) / 64;         // 1563
    int ab = NN / 4;                 // 25000 (NN divisible by 4)
    int tb = (NN + 127) / 128;       // 782

    // CSR build (reused by all 3 layers)
    k_zero<<<nb, 256, 0, stream>>>(cnt, NN);
    k_count<<<eb, 256, 0, stream>>>(ei, cnt);
    k_scan1<<<nb, 256, 0, stream>>>(cnt, rp, bsum);
    k_scan2<<<1, 512, 0, stream>>>(bsum, nb);
    k_scan3<<<nb, 256, 0, stream>>>(rp, bsum);
    k_zero<<<nb, 256, 0, stream>>>(cnt, NN);
    k_scatter<<<eb, 256, 0, stream>>>(ei, rp, cnt, colx);

    // layer 1 (commuted: aggregate x, then per-head GEMM)
    k_avec<<<1, 128, 0, stream>>>(W1, a1s, a1d, pv);
    k_att1<<<tb, 256, 0, stream>>>(x, pv, als, ald);
    k_aggx<<<ab, 256, 0, stream>>>(rp, colx, x, als, ald, xbar);
    k_post1<<<gb, 256, 0, stream>>>(xbar, W1, b1, pa, bufB);
    // layer 2
    k_gemm<<<gb, 256, 0, stream>>>(bufB, W2, a2s, a2d, bufA, als, ald);
    k_agg<0><<<ab, 256, 0, stream>>>(rp, colx, bufA, als, ald, b2, pa, bufB);
    // layer 3 (head mean)
    k_gemm<<<gb, 256, 0, stream>>>(bufB, W3, a3s, a3d, bufA, als, ald);
    k_agg<1><<<ab, 256, 0, stream>>>(rp, colx, bufA, als, ald, b3, pa, bufB);
    // classifier
    k_cls<<<nb, 256, 0, stream>>>(bufB, Wc, bc, out);
}

// Round 4
// 789.029 us; speedup vs baseline: 1.1434x; 1.0464x over previous
//
#include <hip/hip_runtime.h>
#include <stdint.h>

#define NN 100000
#define NE 1600000
#define ET (NE + NN)
#define HC 128
#define HID 64
#define NCLS 12
#define CAP 256

typedef _Float16 f16;
typedef _Float16 f16x2 __attribute__((ext_vector_type(2)));
typedef _Float16 f16x4 __attribute__((ext_vector_type(4)));

// ---------- CSR build ----------
__global__ void k_zero(int* p, int n) {
    int i = blockIdx.x * 256 + threadIdx.x;
    if (i < n) p[i] = 0;
}

__global__ void k_count(const int* __restrict__ ei, int* __restrict__ cnt) {
    int i = blockIdx.x * 256 + threadIdx.x;
    if (i >= ET) return;
    int d = (i < NE) ? ei[NE + i] : (i - NE);
    atomicAdd(&cnt[d], 1);
}

__global__ void k_scan1(const int* __restrict__ cnt, int* __restrict__ rp, int* __restrict__ bsum) {
    __shared__ int s[256];
    int tid = threadIdx.x;
    int i = blockIdx.x * 256 + tid;
    int v = (i < NN) ? cnt[i] : 0;
    s[tid] = v;
    __syncthreads();
    for (int o = 1; o < 256; o <<= 1) {
        int t = (tid >= o) ? s[tid - o] : 0;
        __syncthreads();
        s[tid] += t;
        __syncthreads();
    }
    if (i < NN) rp[i + 1] = s[tid];
    if (tid == 255) bsum[blockIdx.x] = s[255];
}

__global__ void k_scan2(int* __restrict__ bsum, int nb) {
    __shared__ int s[512];
    int tid = threadIdx.x;
    int v = (tid < nb) ? bsum[tid] : 0;
    s[tid] = v;
    __syncthreads();
    for (int o = 1; o < 512; o <<= 1) {
        int t = (tid >= o) ? s[tid - o] : 0;
        __syncthreads();
        s[tid] += t;
        __syncthreads();
    }
    if (tid < nb) bsum[tid] = s[tid] - v;  // exclusive
}

__global__ void k_scan3(int* __restrict__ rp, const int* __restrict__ bsum) {
    int i = blockIdx.x * 256 + threadIdx.x;
    if (i >= NN) return;
    rp[i + 1] += bsum[i >> 8];
    if (i == 0) rp[0] = 0;
}

__global__ void k_scatter(const int* __restrict__ ei, const int* __restrict__ rp,
                          int* __restrict__ fill, int* __restrict__ colx) {
    int i = blockIdx.x * 256 + threadIdx.x;
    if (i >= ET) return;
    int s, d;
    if (i < NE) { s = ei[i]; d = ei[NE + i]; } else { s = d = i - NE; }
    int pos = rp[d] + atomicAdd(&fill[d], 1);
    colx[pos] = s;
}

// ---------- x f32 -> fp16 ----------
__global__ __launch_bounds__(256) void k_xh(const float* __restrict__ x, f16* __restrict__ x16) {
    int i = blockIdx.x * 256 + threadIdx.x;
    if (i >= NN * 8) return;
    float4 v = ((const float4*)x)[i];
    f16x4 o;
    o[0] = (f16)v.x; o[1] = (f16)v.y; o[2] = (f16)v.z; o[3] = (f16)v.w;
    ((f16x4*)x16)[i] = o;
}

// ---------- layer-1 projected attention vectors: pv[sd][h][32] ----------
__global__ void k_avec(const float* __restrict__ W1, const float* __restrict__ a1s,
                       const float* __restrict__ a1d, float* __restrict__ pv) {
    int t = threadIdx.x;  // 128 threads
    int sd = t >> 6, h = (t >> 5) & 1, f = t & 31;
    const float* a = sd ? a1d : a1s;
    float acc = 0.f;
    for (int c = 0; c < 64; c++) acc = fmaf(W1[f * HC + h * 64 + c], a[h * 64 + c], acc);
    pv[t] = acc;
}

// ---------- layer-1 logits from x: als/ald[2n+h] = x[n]·pv[h] ----------
__global__ __launch_bounds__(256) void k_att1(const float* __restrict__ x,
                                              const float* __restrict__ pv,
                                              float* __restrict__ als, float* __restrict__ ald) {
    __shared__ float sIn[128 * 33];
    __shared__ float spv[128];
    int t = threadIdx.x;
    long n0 = (long)blockIdx.x * 128;
    if (t < 128) spv[t] = pv[t];
    for (int c = t; c < 128 * 8; c += 256) {
        int row = c >> 3, col = (c & 7) * 4;
        long gn = n0 + row;
        float4 v = make_float4(0.f, 0.f, 0.f, 0.f);
        if (gn < NN) v = *(const float4*)(x + gn * 32 + col);
        float* dst = &sIn[row * 33 + col];
        dst[0] = v.x; dst[1] = v.y; dst[2] = v.z; dst[3] = v.w;
    }
    __syncthreads();
    int n = t >> 1, h = t & 1;
    long gn = n0 + n;
    if (gn >= NN) return;
    const float* row = &sIn[n * 33];
    const float* as_ = &spv[h * 32];
    const float* ad_ = &spv[64 + h * 32];
    float s_ = 0.f, d_ = 0.f;
#pragma unroll
    for (int f = 0; f < 32; f++) {
        float v = row[f];
        s_ = fmaf(v, as_[f], s_);
        d_ = fmaf(v, ad_[f], d_);
    }
    als[2 * gn + h] = s_;
    ald[2 * gn + h] = d_;
}

// ---------- layer-1 aggregation: gather x16 (32ch), out xbar[N][2][32] f32 ----------
__global__ __launch_bounds__(256) void k_aggx(const int* __restrict__ rp, const int* __restrict__ colx,
                                              const f16* __restrict__ x16,
                                              const float* __restrict__ als, const float* __restrict__ ald,
                                              float* __restrict__ xbar) {
    __shared__ float4 sE[4][CAP];
    int wv = threadIdx.x >> 6, lane = threadIdx.x & 63;
    int wid = blockIdx.x * 4 + wv;
    int start = rp[wid], end = rp[wid + 1], deg = end - start;
    float2 adv = *(const float2*)(ald + 2 * wid);
    float den0 = 0.f, den1 = 0.f;
    for (int j = start + lane; j < end; j += 64) {
        int s = colx[j];
        float2 asv = *(const float2*)(als + 2 * s);
        float e0 = asv.x + adv.x, e1 = asv.y + adv.y;
        e0 = fmaxf(e0, 0.2f * e0);
        e1 = fmaxf(e1, 0.2f * e1);
        float w0 = __expf(e0), w1 = __expf(e1);
        den0 += w0; den1 += w1;
        int idx = j - start;
        if (idx < CAP) {
            float4 e; e.x = __int_as_float(s); e.y = w0; e.z = w1; e.w = 0.f;
            sE[wv][idx] = e;
        }
    }
#pragma unroll
    for (int o = 32; o; o >>= 1) { den0 += __shfl_xor(den0, o); den1 += __shfl_xor(den1, o); }
    __syncthreads();
    int ch = lane & 31;
    bool hi_ = lane >= 32;
    float acc = 0.f;
    int nfast = deg < CAP ? deg : CAP;
#pragma unroll 2
    for (int jj = 0; jj < nfast; ++jj) {
        float4 e = sE[wv][jj];
        int s = __builtin_amdgcn_readfirstlane(__float_as_int(e.x));
        float w = hi_ ? e.z : e.y;
        acc = fmaf(w, (float)x16[(long)s * 32 + ch], acc);
    }
    for (int jj = CAP; jj < deg; ++jj) {  // overflow fallback (rare/never)
        int s = colx[start + jj];
        float2 asv = *(const float2*)(als + 2 * s);
        float e0 = asv.x + adv.x, e1 = asv.y + adv.y;
        e0 = fmaxf(e0, 0.2f * e0);
        e1 = fmaxf(e1, 0.2f * e1);
        float w = hi_ ? __expf(e1) : __expf(e0);
        acc = fmaf(w, (float)x16[(long)s * 32 + ch], acc);
    }
    acc *= 1.0f / (hi_ ? den1 : den0);
    xbar[(long)wid * 64 + lane] = acc;
}

// ---------- layer-1 post GEMM (block-diag K=32/head) + bias + prelu ----------
__global__ __launch_bounds__(256) void k_post1(const float* __restrict__ xb,
                                               const float* __restrict__ W1,
                                               const float* __restrict__ b1,
                                               const float* __restrict__ pap,
                                               float* __restrict__ outp) {
    __shared__ __align__(16) float sIn[64 * 64];
    __shared__ __align__(16) float sW[32 * HC];
    __shared__ float sB[HC];
    int tid = threadIdx.x;
    long n0 = (long)blockIdx.x * 64;
    for (int c = tid; c < 64 * 16; c += 256) {
        int row = c >> 4, col = (c & 15) * 4;
        long gn = n0 + row;
        float4 v = make_float4(0.f, 0.f, 0.f, 0.f);
        if (gn < NN) v = *(const float4*)(xb + gn * 64 + col);
        *(float4*)(sIn + row * 64 + col) = v;
    }
    for (int c = tid; c < 32 * HC / 4; c += 256) ((float4*)sW)[c] = ((const float4*)W1)[c];
    if (tid < HC) sB[tid] = b1[tid];
    __syncthreads();
    int cg = tid & 31, ng = tid >> 5, head = cg >> 4;
    float4 acc[8];
#pragma unroll
    for (int i = 0; i < 8; i++) acc[i] = make_float4(0.f, 0.f, 0.f, 0.f);
    for (int k = 0; k < 32; k++) {
        float4 w = *(const float4*)(sW + k * HC + cg * 4);
#pragma unroll
        for (int i = 0; i < 8; i++) {
            float a = sIn[(ng * 8 + i) * 64 + head * 32 + k];
            acc[i].x = fmaf(a, w.x, acc[i].x);
            acc[i].y = fmaf(a, w.y, acc[i].y);
            acc[i].z = fmaf(a, w.z, acc[i].z);
            acc[i].w = fmaf(a, w.w, acc[i].w);
        }
    }
    float pa = pap[0];
    float4 b = *(const float4*)(sB + cg * 4);
#pragma unroll
    for (int i = 0; i < 8; i++) {
        long n = n0 + ng * 8 + i;
        if (n < NN) {
            float4 o;
            o.x = acc[i].x + b.x; o.y = acc[i].y + b.y;
            o.z = acc[i].z + b.z; o.w = acc[i].w + b.w;
            o.x = o.x >= 0.f ? o.x : pa * o.x;
            o.y = o.y >= 0.f ? o.y : pa * o.y;
            o.z = o.z >= 0.f ? o.z : pa * o.z;
            o.w = o.w >= 0.f ? o.w : pa * o.w;
            *(float4*)(outp + n * HC + cg * 4) = o;
        }
    }
}

// ---------- GEMM h16 = in @ W (K=128) + fused attention projections ----------
__global__ __launch_bounds__(256) void k_gemm(const float* __restrict__ xg,
                                              const float* __restrict__ Wg,
                                              const float* __restrict__ avs,
                                              const float* __restrict__ avd,
                                              f16* __restrict__ h16,
                                              float* __restrict__ als, float* __restrict__ ald) {
    constexpr int K = 128, KT = 64;
    __shared__ __align__(16) float sIn[64 * KT];
    __shared__ __align__(16) float sW[KT * HC];
    __shared__ float sas[HC], sad[HC];
    int tid = threadIdx.x;
    long n0 = (long)blockIdx.x * 64;
    if (tid < HC) { sas[tid] = avs[tid]; sad[tid] = avd[tid]; }
    int cg = tid & 31, ng = tid >> 5;
    float4 acc[8];
#pragma unroll
    for (int i = 0; i < 8; i++) acc[i] = make_float4(0.f, 0.f, 0.f, 0.f);

    for (int kt = 0; kt < K; kt += KT) {
        __syncthreads();
        const float4* wsrc = (const float4*)(Wg + (long)kt * HC);
        for (int c = tid; c < KT * HC / 4; c += 256) ((float4*)sW)[c] = wsrc[c];
        for (int c = tid; c < 64 * KT / 4; c += 256) {
            int row = c / (KT / 4), kc = c % (KT / 4);
            long gn = n0 + row;
            float4 v = make_float4(0.f, 0.f, 0.f, 0.f);
            if (gn < NN) v = *(const float4*)(xg + gn * K + kt + kc * 4);
            *(float4*)(sIn + row * KT + kc * 4) = v;
        }
        __syncthreads();
        for (int k = 0; k < KT; k += 4) {
            float4 w0 = *(const float4*)(sW + (k + 0) * HC + cg * 4);
            float4 w1 = *(const float4*)(sW + (k + 1) * HC + cg * 4);
            float4 w2 = *(const float4*)(sW + (k + 2) * HC + cg * 4);
            float4 w3 = *(const float4*)(sW + (k + 3) * HC + cg * 4);
#pragma unroll
            for (int i = 0; i < 8; i++) {
                float4 a = *(const float4*)(sIn + (ng * 8 + i) * KT + k);
                acc[i].x = fmaf(a.x, w0.x, acc[i].x); acc[i].y = fmaf(a.x, w0.y, acc[i].y);
                acc[i].z = fmaf(a.x, w0.z, acc[i].z); acc[i].w = fmaf(a.x, w0.w, acc[i].w);
                acc[i].x = fmaf(a.y, w1.x, acc[i].x); acc[i].y = fmaf(a.y, w1.y, acc[i].y);
                acc[i].z = fmaf(a.y, w1.z, acc[i].z); acc[i].w = fmaf(a.y, w1.w, acc[i].w);
                acc[i].x = fmaf(a.z, w2.x, acc[i].x); acc[i].y = fmaf(a.z, w2.y, acc[i].y);
                acc[i].z = fmaf(a.z, w2.z, acc[i].z); acc[i].w = fmaf(a.z, w2.w, acc[i].w);
                acc[i].x = fmaf(a.w, w3.x, acc[i].x); acc[i].y = fmaf(a.w, w3.y, acc[i].y);
                acc[i].z = fmaf(a.w, w3.z, acc[i].z); acc[i].w = fmaf(a.w, w3.w, acc[i].w);
            }
        }
    }
    int head = cg >> 4;
#pragma unroll
    for (int i = 0; i < 8; i++) {
        long n = n0 + ng * 8 + i;
        if (n < NN) {
            f16x4 o;
            o[0] = (f16)acc[i].x; o[1] = (f16)acc[i].y;
            o[2] = (f16)acc[i].z; o[3] = (f16)acc[i].w;
            *(f16x4*)(h16 + n * HC + cg * 4) = o;
        }
        // fused proj: reduce acc·a over this head's 16-lane column group (f32 accumulators)
        const float* ap = (const float*)&acc[i];
        float s_ = 0.f, d_ = 0.f;
#pragma unroll
        for (int j = 0; j < 4; j++) {
            int c = cg * 4 + j;
            s_ = fmaf(ap[j], sas[c], s_);
            d_ = fmaf(ap[j], sad[c], d_);
        }
#pragma unroll
        for (int o = 8; o; o >>= 1) { s_ += __shfl_xor(s_, o); d_ += __shfl_xor(d_, o); }
        if ((cg & 15) == 0 && n < NN) {
            als[2 * n + head] = s_;
            ald[2 * n + head] = d_;
        }
    }
}

// ---------- aggregation over h16 (128ch): single-pass, LDS-cached weights ----------
template <int MEAN>
__global__ __launch_bounds__(256) void k_agg(const int* __restrict__ rp, const int* __restrict__ colx,
                                             const f16* __restrict__ h,
                                             const float* __restrict__ als, const float* __restrict__ ald,
                                             const float* __restrict__ bias,
                                             const float* __restrict__ pap,
                                             float* __restrict__ outp) {
    __shared__ float4 sE[4][CAP];
    int wv = threadIdx.x >> 6, lane = threadIdx.x & 63;
    int wid = blockIdx.x * 4 + wv;
    int start = rp[wid], end = rp[wid + 1], deg = end - start;
    float2 adv = *(const float2*)(ald + 2 * wid);
    float den0 = 0.f, den1 = 0.f;
    for (int j = start + lane; j < end; j += 64) {
        int s = colx[j];
        float2 asv = *(const float2*)(als + 2 * s);
        float e0 = asv.x + adv.x, e1 = asv.y + adv.y;
        e0 = fmaxf(e0, 0.2f * e0);
        e1 = fmaxf(e1, 0.2f * e1);
        float w0 = __expf(e0), w1 = __expf(e1);
        den0 += w0; den1 += w1;
        int idx = j - start;
        if (idx < CAP) {
            float4 e; e.x = __int_as_float(s); e.y = w0; e.z = w1; e.w = 0.f;
            sE[wv][idx] = e;
        }
    }
#pragma unroll
    for (int o = 32; o; o >>= 1) { den0 += __shfl_xor(den0, o); den1 += __shfl_xor(den1, o); }
    __syncthreads();
    bool hi_ = lane >= 32;
    float ax = 0.f, ay = 0.f;
    int nfast = deg < CAP ? deg : CAP;
#pragma unroll 2
    for (int jj = 0; jj < nfast; ++jj) {
        float4 e = sE[wv][jj];
        int s = __builtin_amdgcn_readfirstlane(__float_as_int(e.x));
        float w = hi_ ? e.z : e.y;
        f16x2 hv = *(const f16x2*)(h + (long)s * HC + lane * 2);
        ax = fmaf(w, (float)hv[0], ax);
        ay = fmaf(w, (float)hv[1], ay);
    }
    for (int jj = CAP; jj < deg; ++jj) {  // overflow fallback (rare/never)
        int s = colx[start + jj];
        float2 asv = *(const float2*)(als + 2 * s);
        float e0 = asv.x + adv.x, e1 = asv.y + adv.y;
        e0 = fmaxf(e0, 0.2f * e0);
        e1 = fmaxf(e1, 0.2f * e1);
        float w = hi_ ? __expf(e1) : __expf(e0);
        f16x2 hv = *(const f16x2*)(h + (long)s * HC + lane * 2);
        ax = fmaf(w, (float)hv[0], ax);
        ay = fmaf(w, (float)hv[1], ay);
    }
    float inv = 1.0f / (hi_ ? den1 : den0);
    float pa = pap[0];
    if (!MEAN) {
        float2 bu = *(const float2*)(bias + lane * 2);
        float o0 = ax * inv + bu.x;
        float o1 = ay * inv + bu.y;
        o0 = o0 >= 0.f ? o0 : pa * o0;
        o1 = o1 >= 0.f ? o1 : pa * o1;
        *(float2*)(outp + (long)wid * HC + lane * 2) = make_float2(o0, o1);
    } else {
        float v0 = ax * inv, v1 = ay * inv;
        float p0 = __shfl_xor(v0, 32), p1 = __shfl_xor(v1, 32);
        if (lane < 32) {
            float2 bu = *(const float2*)(bias + lane * 2);
            float o0 = 0.5f * (v0 + p0) + bu.x;
            float o1 = 0.5f * (v1 + p1) + bu.y;
            o0 = o0 >= 0.f ? o0 : pa * o0;
            o1 = o1 >= 0.f ? o1 : pa * o1;
            *(float2*)(outp + (long)wid * HID + lane * 2) = make_float2(o0, o1);
        }
    }
}

// ---------- classifier ----------
__global__ __launch_bounds__(256) void k_cls(const float* __restrict__ hin,
                                             const float* __restrict__ Wc,
                                             const float* __restrict__ bcp,
                                             float* __restrict__ outp) {
    __shared__ float sW[HID * NCLS];
    __shared__ float sb[NCLS];
    int tid = threadIdx.x;
    for (int c = tid; c < HID * NCLS; c += 256) sW[c] = Wc[c];
    if (tid < NCLS) sb[tid] = bcp[tid];
    __syncthreads();
    int n = blockIdx.x * 256 + tid;
    if (n >= NN) return;
    float o[NCLS];
#pragma unroll
    for (int k = 0; k < NCLS; k++) o[k] = sb[k];
    const float* row = hin + (long)n * HID;
#pragma unroll 8
    for (int c = 0; c < HID; c++) {
        float v = row[c];
#pragma unroll
        for (int k = 0; k < NCLS; k++) o[k] = fmaf(v, sW[c * NCLS + k], o[k]);
    }
#pragma unroll
    for (int k = 0; k < NCLS; k += 2)
        *(float2*)(outp + (long)n * NCLS + k) = make_float2(o[k], o[k + 1]);
}

extern "C" void kernel_launch(void* const* d_in, const int* in_sizes, int n_in,
                              void* d_out, int out_size, void* d_ws, size_t ws_size,
                              hipStream_t stream) {
    const float* x   = (const float*)d_in[0];
    const int*   ei  = (const int*)d_in[1];
    const float* W1  = (const float*)d_in[2];
    const float* a1s = (const float*)d_in[3];
    const float* a1d = (const float*)d_in[4];
    const float* b1  = (const float*)d_in[5];
    const float* W2  = (const float*)d_in[6];
    const float* a2s = (const float*)d_in[7];
    const float* a2d = (const float*)d_in[8];
    const float* b2  = (const float*)d_in[9];
    const float* W3  = (const float*)d_in[10];
    const float* a3s = (const float*)d_in[11];
    const float* a3d = (const float*)d_in[12];
    const float* b3  = (const float*)d_in[13];
    const float* pa  = (const float*)d_in[14];
    const float* Wc  = (const float*)d_in[15];
    const float* bc  = (const float*)d_in[16];
    float* out = (float*)d_out;

    char* w = (char*)d_ws;
    size_t off = 0;
    auto take = [&](size_t b) { void* p = w + off; off += (b + 255) & ~(size_t)255; return p; };
    int* cnt    = (int*)take((size_t)NN * 4);
    int* rp     = (int*)take((size_t)(NN + 1) * 4);
    int* bsum   = (int*)take(2048);
    int* colx   = (int*)take((size_t)ET * 4);
    float* als  = (float*)take((size_t)NN * 8);
    float* ald  = (float*)take((size_t)NN * 8);
    float* pv   = (float*)take(512);
    f16* x16    = (f16*)take((size_t)NN * 32 * 2);
    f16* h16    = (f16*)take((size_t)NN * HC * 2);
    float* xbar = (float*)take((size_t)NN * 64 * 4);
    float* bufB = (float*)take((size_t)NN * HC * 4);

    int nb = (NN + 255) / 256;       // 391
    int eb = (ET + 255) / 256;
    int gb = (NN + 63) / 64;         // 1563
    int ab = NN / 4;                 // 25000
    int tb = (NN + 127) / 128;       // 782
    int xb = (NN * 8 + 255) / 256;   // 3125

    // CSR build (reused by all 3 layers)
    k_zero<<<nb, 256, 0, stream>>>(cnt, NN);
    k_count<<<eb, 256, 0, stream>>>(ei, cnt);
    k_scan1<<<nb, 256, 0, stream>>>(cnt, rp, bsum);
    k_scan2<<<1, 512, 0, stream>>>(bsum, nb);
    k_scan3<<<nb, 256, 0, stream>>>(rp, bsum);
    k_zero<<<nb, 256, 0, stream>>>(cnt, NN);
    k_scatter<<<eb, 256, 0, stream>>>(ei, rp, cnt, colx);

    // layer 1 (commuted: aggregate x, then per-head GEMM)
    k_xh<<<xb, 256, 0, stream>>>(x, x16);
    k_avec<<<1, 128, 0, stream>>>(W1, a1s, a1d, pv);
    k_att1<<<tb, 256, 0, stream>>>(x, pv, als, ald);
    k_aggx<<<ab, 256, 0, stream>>>(rp, colx, x16, als, ald, xbar);
    k_post1<<<gb, 256, 0, stream>>>(xbar, W1, b1, pa, bufB);
    // layer 2
    k_gemm<<<gb, 256, 0, stream>>>(bufB, W2, a2s, a2d, h16, als, ald);
    k_agg<0><<<ab, 256, 0, stream>>>(rp, colx, h16, als, ald, b2, pa, bufB);
    // layer 3 (head mean)
    k_gemm<<<gb, 256, 0, stream>>>(bufB, W3, a3s, a3d, h16, als, ald);
    k_agg<1><<<ab, 256, 0, stream>>>(rp, colx, h16, als, ald, b3, pa, bufB);
    // classifier
    k_cls<<<nb, 256, 0, stream>>>(bufB, Wc, bc, out);
}

// Round 5
// 647.992 us; speedup vs baseline: 1.3923x; 1.2177x over previous
//
#include <hip/hip_runtime.h>
#include <stdint.h>

#define NN 100000
#define NE 1600000
#define ET (NE + NN)
#define HC 128
#define HID 64
#define NCLS 12

typedef _Float16 f16;
typedef _Float16 f16x2 __attribute__((ext_vector_type(2)));
typedef _Float16 f16x4 __attribute__((ext_vector_type(4)));
typedef _Float16 f16x8 __attribute__((ext_vector_type(8)));

// ---------- CSR build ----------
__global__ void k_zero(int* p, int n) {
    int i = blockIdx.x * 256 + threadIdx.x;
    if (i < n) p[i] = 0;
}

__global__ void k_count(const int* __restrict__ ei, int* __restrict__ cnt) {
    int i = blockIdx.x * 256 + threadIdx.x;
    if (i >= ET) return;
    int d = (i < NE) ? ei[NE + i] : (i - NE);
    atomicAdd(&cnt[d], 1);
}

__global__ void k_scan1(const int* __restrict__ cnt, int* __restrict__ rp, int* __restrict__ bsum) {
    __shared__ int s[256];
    int tid = threadIdx.x;
    int i = blockIdx.x * 256 + tid;
    int v = (i < NN) ? cnt[i] : 0;
    s[tid] = v;
    __syncthreads();
    for (int o = 1; o < 256; o <<= 1) {
        int t = (tid >= o) ? s[tid - o] : 0;
        __syncthreads();
        s[tid] += t;
        __syncthreads();
    }
    if (i < NN) rp[i + 1] = s[tid];
    if (tid == 255) bsum[blockIdx.x] = s[255];
}

__global__ void k_scan2(int* __restrict__ bsum, int nb) {
    __shared__ int s[512];
    int tid = threadIdx.x;
    int v = (tid < nb) ? bsum[tid] : 0;
    s[tid] = v;
    __syncthreads();
    for (int o = 1; o < 512; o <<= 1) {
        int t = (tid >= o) ? s[tid - o] : 0;
        __syncthreads();
        s[tid] += t;
        __syncthreads();
    }
    if (tid < nb) bsum[tid] = s[tid] - v;  // exclusive
}

__global__ void k_scan3(int* __restrict__ rp, const int* __restrict__ bsum) {
    int i = blockIdx.x * 256 + threadIdx.x;
    if (i >= NN) return;
    rp[i + 1] += bsum[i >> 8];
    if (i == 0) rp[0] = 0;
}

__global__ void k_scatter(const int* __restrict__ ei, const int* __restrict__ rp,
                          int* __restrict__ fill, int* __restrict__ colx) {
    int i = blockIdx.x * 256 + threadIdx.x;
    if (i >= ET) return;
    int s, d;
    if (i < NE) { s = ei[i]; d = ei[NE + i]; } else { s = d = i - NE; }
    int pos = rp[d] + atomicAdd(&fill[d], 1);
    colx[pos] = s;
}

// ---------- x f32 -> fp16 ----------
__global__ __launch_bounds__(256) void k_xh(const float* __restrict__ x, f16* __restrict__ x16) {
    int i = blockIdx.x * 256 + threadIdx.x;
    if (i >= NN * 8) return;
    float4 v = ((const float4*)x)[i];
    f16x4 o;
    o[0] = (f16)v.x; o[1] = (f16)v.y; o[2] = (f16)v.z; o[3] = (f16)v.w;
    ((f16x4*)x16)[i] = o;
}

// ---------- layer-1 projected attention vectors: pv[sd][h][32] ----------
__global__ void k_avec(const float* __restrict__ W1, const float* __restrict__ a1s,
                       const float* __restrict__ a1d, float* __restrict__ pv) {
    int t = threadIdx.x;  // 128 threads
    int sd = t >> 6, h = (t >> 5) & 1, f = t & 31;
    const float* a = sd ? a1d : a1s;
    float acc = 0.f;
    for (int c = 0; c < 64; c++) acc = fmaf(W1[f * HC + h * 64 + c], a[h * 64 + c], acc);
    pv[t] = acc;
}

// ---------- layer-1 logits from x: als/ald[2n+h] = x[n]·pv[h] ----------
__global__ __launch_bounds__(256) void k_att1(const float* __restrict__ x,
                                              const float* __restrict__ pv,
                                              float* __restrict__ als, float* __restrict__ ald) {
    __shared__ float sIn[128 * 33];
    __shared__ float spv[128];
    int t = threadIdx.x;
    long n0 = (long)blockIdx.x * 128;
    if (t < 128) spv[t] = pv[t];
    for (int c = t; c < 128 * 8; c += 256) {
        int row = c >> 3, col = (c & 7) * 4;
        long gn = n0 + row;
        float4 v = make_float4(0.f, 0.f, 0.f, 0.f);
        if (gn < NN) v = *(const float4*)(x + gn * 32 + col);
        float* dst = &sIn[row * 33 + col];
        dst[0] = v.x; dst[1] = v.y; dst[2] = v.z; dst[3] = v.w;
    }
    __syncthreads();
    int n = t >> 1, h = t & 1;
    long gn = n0 + n;
    if (gn >= NN) return;
    const float* row = &sIn[n * 33];
    const float* as_ = &spv[h * 32];
    const float* ad_ = &spv[64 + h * 32];
    float s_ = 0.f, d_ = 0.f;
#pragma unroll
    for (int f = 0; f < 32; f++) {
        float v = row[f];
        s_ = fmaf(v, as_[f], s_);
        d_ = fmaf(v, ad_[f], d_);
    }
    als[2 * gn + h] = s_;
    ald[2 * gn + h] = d_;
}

// ---------- layer-1 aggregation: 16 edges/iter, 4 lanes/edge, out xbar[N][2][32] ----------
__global__ __launch_bounds__(256) void k_aggx(const int* __restrict__ rp, const int* __restrict__ colx,
                                              const f16* __restrict__ x16,
                                              const float* __restrict__ als, const float* __restrict__ ald,
                                              float* __restrict__ xbar) {
    int wid = blockIdx.x * 4 + (threadIdx.x >> 6);
    int lane = threadIdx.x & 63;
    int g = lane >> 2, li = lane & 3;          // 16 edge-groups x 4 lanes
    int start = rp[wid], end = rp[wid + 1];
    float2 adv = *(const float2*)(ald + 2 * wid);
    float a0[8], a1[8];
#pragma unroll
    for (int k = 0; k < 8; k++) { a0[k] = 0.f; a1[k] = 0.f; }
    float ws0 = 0.f, ws1 = 0.f;
#pragma unroll 2
    for (int j0 = start; j0 < end; j0 += 16) {
        int j = j0 + g;
        int jc = j < end ? j : end - 1;
        int s = colx[jc];
        float2 asv = *(const float2*)(als + 2 * s);
        float e0 = asv.x + adv.x, e1 = asv.y + adv.y;
        e0 = fmaxf(e0, 0.2f * e0);
        e1 = fmaxf(e1, 0.2f * e1);
        float w0 = __expf(e0), w1 = __expf(e1);
        if (j >= end) { w0 = 0.f; w1 = 0.f; }
        ws0 += w0; ws1 += w1;
        f16x8 xv = *(const f16x8*)(x16 + (long)s * 32 + li * 8);
#pragma unroll
        for (int k = 0; k < 8; k++) {
            float f = (float)xv[k];
            a0[k] = fmaf(w0, f, a0[k]);
            a1[k] = fmaf(w1, f, a1[k]);
        }
    }
#pragma unroll
    for (int o = 4; o <= 32; o <<= 1) {
        ws0 += __shfl_xor(ws0, o);
        ws1 += __shfl_xor(ws1, o);
#pragma unroll
        for (int k = 0; k < 8; k++) {
            a0[k] += __shfl_xor(a0[k], o);
            a1[k] += __shfl_xor(a1[k], o);
        }
    }
    float inv0 = 1.0f / ws0, inv1 = 1.0f / ws1;
    int head = g >> 3, q = g & 7;
    float val = head ? a1[q] * inv1 : a0[q] * inv0;
    xbar[(long)wid * 64 + head * 32 + li * 8 + q] = val;
}

// ---------- layer-1 post GEMM (block-diag K=32/head) + bias + prelu ----------
__global__ __launch_bounds__(256) void k_post1(const float* __restrict__ xb,
                                               const float* __restrict__ W1,
                                               const float* __restrict__ b1,
                                               const float* __restrict__ pap,
                                               float* __restrict__ outp) {
    __shared__ __align__(16) float sIn[64 * 64];
    __shared__ __align__(16) float sW[32 * HC];
    __shared__ float sB[HC];
    int tid = threadIdx.x;
    long n0 = (long)blockIdx.x * 64;
    for (int c = tid; c < 64 * 16; c += 256) {
        int row = c >> 4, col = (c & 15) * 4;
        long gn = n0 + row;
        float4 v = make_float4(0.f, 0.f, 0.f, 0.f);
        if (gn < NN) v = *(const float4*)(xb + gn * 64 + col);
        *(float4*)(sIn + row * 64 + col) = v;
    }
    for (int c = tid; c < 32 * HC / 4; c += 256) ((float4*)sW)[c] = ((const float4*)W1)[c];
    if (tid < HC) sB[tid] = b1[tid];
    __syncthreads();
    int cg = tid & 31, ng = tid >> 5, head = cg >> 4;
    float4 acc[8];
#pragma unroll
    for (int i = 0; i < 8; i++) acc[i] = make_float4(0.f, 0.f, 0.f, 0.f);
    for (int k = 0; k < 32; k++) {
        float4 w = *(const float4*)(sW + k * HC + cg * 4);
#pragma unroll
        for (int i = 0; i < 8; i++) {
            float a = sIn[(ng * 8 + i) * 64 + head * 32 + k];
            acc[i].x = fmaf(a, w.x, acc[i].x);
            acc[i].y = fmaf(a, w.y, acc[i].y);
            acc[i].z = fmaf(a, w.z, acc[i].z);
            acc[i].w = fmaf(a, w.w, acc[i].w);
        }
    }
    float pa = pap[0];
    float4 b = *(const float4*)(sB + cg * 4);
#pragma unroll
    for (int i = 0; i < 8; i++) {
        long n = n0 + ng * 8 + i;
        if (n < NN) {
            float4 o;
            o.x = acc[i].x + b.x; o.y = acc[i].y + b.y;
            o.z = acc[i].z + b.z; o.w = acc[i].w + b.w;
            o.x = o.x >= 0.f ? o.x : pa * o.x;
            o.y = o.y >= 0.f ? o.y : pa * o.y;
            o.z = o.z >= 0.f ? o.z : pa * o.z;
            o.w = o.w >= 0.f ? o.w : pa * o.w;
            *(float4*)(outp + n * HC + cg * 4) = o;
        }
    }
}

// ---------- GEMM h16 = in @ W (K=128) + fused attention projections ----------
__global__ __launch_bounds__(256) void k_gemm(const float* __restrict__ xg,
                                              const float* __restrict__ Wg,
                                              const float* __restrict__ avs,
                                              const float* __restrict__ avd,
                                              f16* __restrict__ h16,
                                              float* __restrict__ als, float* __restrict__ ald) {
    constexpr int K = 128, KT = 64;
    __shared__ __align__(16) float sIn[64 * KT];
    __shared__ __align__(16) float sW[KT * HC];
    __shared__ float sas[HC], sad[HC];
    int tid = threadIdx.x;
    long n0 = (long)blockIdx.x * 64;
    if (tid < HC) { sas[tid] = avs[tid]; sad[tid] = avd[tid]; }
    int cg = tid & 31, ng = tid >> 5;
    float4 acc[8];
#pragma unroll
    for (int i = 0; i < 8; i++) acc[i] = make_float4(0.f, 0.f, 0.f, 0.f);

    for (int kt = 0; kt < K; kt += KT) {
        __syncthreads();
        const float4* wsrc = (const float4*)(Wg + (long)kt * HC);
        for (int c = tid; c < KT * HC / 4; c += 256) ((float4*)sW)[c] = wsrc[c];
        for (int c = tid; c < 64 * KT / 4; c += 256) {
            int row = c / (KT / 4), kc = c % (KT / 4);
            long gn = n0 + row;
            float4 v = make_float4(0.f, 0.f, 0.f, 0.f);
            if (gn < NN) v = *(const float4*)(xg + gn * K + kt + kc * 4);
            *(float4*)(sIn + row * KT + kc * 4) = v;
        }
        __syncthreads();
        for (int k = 0; k < KT; k += 4) {
            float4 w0 = *(const float4*)(sW + (k + 0) * HC + cg * 4);
            float4 w1 = *(const float4*)(sW + (k + 1) * HC + cg * 4);
            float4 w2 = *(const float4*)(sW + (k + 2) * HC + cg * 4);
            float4 w3 = *(const float4*)(sW + (k + 3) * HC + cg * 4);
#pragma unroll
            for (int i = 0; i < 8; i++) {
                float4 a = *(const float4*)(sIn + (ng * 8 + i) * KT + k);
                acc[i].x = fmaf(a.x, w0.x, acc[i].x); acc[i].y = fmaf(a.x, w0.y, acc[i].y);
                acc[i].z = fmaf(a.x, w0.z, acc[i].z); acc[i].w = fmaf(a.x, w0.w, acc[i].w);
                acc[i].x = fmaf(a.y, w1.x, acc[i].x); acc[i].y = fmaf(a.y, w1.y, acc[i].y);
                acc[i].z = fmaf(a.y, w1.z, acc[i].z); acc[i].w = fmaf(a.y, w1.w, acc[i].w);
                acc[i].x = fmaf(a.z, w2.x, acc[i].x); acc[i].y = fmaf(a.z, w2.y, acc[i].y);
                acc[i].z = fmaf(a.z, w2.z, acc[i].z); acc[i].w = fmaf(a.z, w2.w, acc[i].w);
                acc[i].x = fmaf(a.w, w3.x, acc[i].x); acc[i].y = fmaf(a.w, w3.y, acc[i].y);
                acc[i].z = fmaf(a.w, w3.z, acc[i].z); acc[i].w = fmaf(a.w, w3.w, acc[i].w);
            }
        }
    }
    int head = cg >> 4;
#pragma unroll
    for (int i = 0; i < 8; i++) {
        long n = n0 + ng * 8 + i;
        if (n < NN) {
            f16x4 o;
            o[0] = (f16)acc[i].x; o[1] = (f16)acc[i].y;
            o[2] = (f16)acc[i].z; o[3] = (f16)acc[i].w;
            *(f16x4*)(h16 + n * HC + cg * 4) = o;
        }
        // fused proj: reduce acc·a over this head's 16-lane column group (f32 accumulators)
        const float* ap = (const float*)&acc[i];
        float s_ = 0.f, d_ = 0.f;
#pragma unroll
        for (int j = 0; j < 4; j++) {
            int c = cg * 4 + j;
            s_ = fmaf(ap[j], sas[c], s_);
            d_ = fmaf(ap[j], sad[c], d_);
        }
#pragma unroll
        for (int o = 8; o; o >>= 1) { s_ += __shfl_xor(s_, o); d_ += __shfl_xor(d_, o); }
        if ((cg & 15) == 0 && n < NN) {
            als[2 * n + head] = s_;
            ald[2 * n + head] = d_;
        }
    }
}

// ---------- aggregation over h16: 4 edges/iter, 16 lanes/edge, single pass ----------
template <int MEAN>
__global__ __launch_bounds__(256) void k_agg(const int* __restrict__ rp, const int* __restrict__ colx,
                                             const f16* __restrict__ h,
                                             const float* __restrict__ als, const float* __restrict__ ald,
                                             const float* __restrict__ bias,
                                             const float* __restrict__ pap,
                                             float* __restrict__ outp) {
    int wid = blockIdx.x * 4 + (threadIdx.x >> 6);
    int lane = threadIdx.x & 63;
    int g = lane >> 4, li = lane & 15;         // 4 edge-groups x 16 lanes
    int start = rp[wid], end = rp[wid + 1];
    float2 adv = *(const float2*)(ald + 2 * wid);
    float acc[8];
#pragma unroll
    for (int k = 0; k < 8; k++) acc[k] = 0.f;
    float ws0 = 0.f, ws1 = 0.f;
    bool head1 = li >= 8;                      // lane's channels li*8..li*8+7 (head = li>=8)
#pragma unroll 2
    for (int j0 = start; j0 < end; j0 += 4) {
        int j = j0 + g;
        int jc = j < end ? j : end - 1;
        int s = colx[jc];
        float2 asv = *(const float2*)(als + 2 * s);
        float e0 = asv.x + adv.x, e1 = asv.y + adv.y;
        e0 = fmaxf(e0, 0.2f * e0);
        e1 = fmaxf(e1, 0.2f * e1);
        float w0 = __expf(e0), w1 = __expf(e1);
        if (j >= end) { w0 = 0.f; w1 = 0.f; }
        ws0 += w0; ws1 += w1;
        f16x8 hv = *(const f16x8*)(h + (long)s * HC + li * 8);
        float wsel = head1 ? w1 : w0;
#pragma unroll
        for (int k = 0; k < 8; k++) acc[k] = fmaf(wsel, (float)hv[k], acc[k]);
    }
    // reduce across the 4 edge-groups
#pragma unroll
    for (int o = 16; o <= 32; o <<= 1) {
        ws0 += __shfl_xor(ws0, o);
        ws1 += __shfl_xor(ws1, o);
#pragma unroll
        for (int k = 0; k < 8; k++) acc[k] += __shfl_xor(acc[k], o);
    }
    float pa = pap[0];
    if (!MEAN) {
        float inv = 1.0f / (head1 ? ws1 : ws0);
        int c = li * 8 + g * 2;
        float2 bu = *(const float2*)(bias + c);
        float o0 = acc[g * 2] * inv + bu.x;
        float o1 = acc[g * 2 + 1] * inv + bu.y;
        o0 = o0 >= 0.f ? o0 : pa * o0;
        o1 = o1 >= 0.f ? o1 : pa * o1;
        *(float2*)(outp + (long)wid * HC + c) = make_float2(o0, o1);
    } else {
        float inv = 1.0f / (head1 ? ws1 : ws0);
        float v0 = acc[g * 2] * inv, v1 = acc[g * 2 + 1] * inv;
        float p0 = __shfl_xor(v0, 8), p1 = __shfl_xor(v1, 8);  // partner head, same in-head ch
        if (!head1) {
            int c = li * 8 + g * 2;
            float2 bu = *(const float2*)(bias + c);
            float o0 = 0.5f * (v0 + p0) + bu.x;
            float o1 = 0.5f * (v1 + p1) + bu.y;
            o0 = o0 >= 0.f ? o0 : pa * o0;
            o1 = o1 >= 0.f ? o1 : pa * o1;
            *(float2*)(outp + (long)wid * HID + c) = make_float2(o0, o1);
        }
    }
}

// ---------- classifier ----------
__global__ __launch_bounds__(256) void k_cls(const float* __restrict__ hin,
                                             const float* __restrict__ Wc,
                                             const float* __restrict__ bcp,
                                             float* __restrict__ outp) {
    __shared__ float sW[HID * NCLS];
    __shared__ float sb[NCLS];
    int tid = threadIdx.x;
    for (int c = tid; c < HID * NCLS; c += 256) sW[c] = Wc[c];
    if (tid < NCLS) sb[tid] = bcp[tid];
    __syncthreads();
    int n = blockIdx.x * 256 + tid;
    if (n >= NN) return;
    float o[NCLS];
#pragma unroll
    for (int k = 0; k < NCLS; k++) o[k] = sb[k];
    const float* row = hin + (long)n * HID;
#pragma unroll 8
    for (int c = 0; c < HID; c++) {
        float v = row[c];
#pragma unroll
        for (int k = 0; k < NCLS; k++) o[k] = fmaf(v, sW[c * NCLS + k], o[k]);
    }
#pragma unroll
    for (int k = 0; k < NCLS; k += 2)
        *(float2*)(outp + (long)n * NCLS + k) = make_float2(o[k], o[k + 1]);
}

extern "C" void kernel_launch(void* const* d_in, const int* in_sizes, int n_in,
                              void* d_out, int out_size, void* d_ws, size_t ws_size,
                              hipStream_t stream) {
    const float* x   = (const float*)d_in[0];
    const int*   ei  = (const int*)d_in[1];
    const float* W1  = (const float*)d_in[2];
    const float* a1s = (const float*)d_in[3];
    const float* a1d = (const float*)d_in[4];
    const float* b1  = (const float*)d_in[5];
    const float* W2  = (const float*)d_in[6];
    const float* a2s = (const float*)d_in[7];
    const float* a2d = (const float*)d_in[8];
    const float* b2  = (const float*)d_in[9];
    const float* W3  = (const float*)d_in[10];
    const float* a3s = (const float*)d_in[11];
    const float* a3d = (const float*)d_in[12];
    const float* b3  = (const float*)d_in[13];
    const float* pa  = (const float*)d_in[14];
    const float* Wc  = (const float*)d_in[15];
    const float* bc  = (const float*)d_in[16];
    float* out = (float*)d_out;

    char* w = (char*)d_ws;
    size_t off = 0;
    auto take = [&](size_t b) { void* p = w + off; off += (b + 255) & ~(size_t)255; return p; };
    int* cnt    = (int*)take((size_t)NN * 4);
    int* rp     = (int*)take((size_t)(NN + 1) * 4);
    int* bsum   = (int*)take(2048);
    int* colx   = (int*)take((size_t)ET * 4);
    float* als  = (float*)take((size_t)NN * 8);
    float* ald  = (float*)take((size_t)NN * 8);
    float* pv   = (float*)take(512);
    f16* x16    = (f16*)take((size_t)NN * 32 * 2);
    f16* h16    = (f16*)take((size_t)NN * HC * 2);
    float* xbar = (float*)take((size_t)NN * 64 * 4);
    float* bufB = (float*)take((size_t)NN * HC * 4);

    int nb = (NN + 255) / 256;       // 391
    int eb = (ET + 255) / 256;
    int gb = (NN + 63) / 64;         // 1563
    int ab = NN / 4;                 // 25000
    int tb = (NN + 127) / 128;       // 782
    int xb = (NN * 8 + 255) / 256;   // 3125

    // CSR build (reused by all 3 layers)
    k_zero<<<nb, 256, 0, stream>>>(cnt, NN);
    k_count<<<eb, 256, 0, stream>>>(ei, cnt);
    k_scan1<<<nb, 256, 0, stream>>>(cnt, rp, bsum);
    k_scan2<<<1, 512, 0, stream>>>(bsum, nb);
    k_scan3<<<nb, 256, 0, stream>>>(rp, bsum);
    k_zero<<<nb, 256, 0, stream>>>(cnt, NN);
    k_scatter<<<eb, 256, 0, stream>>>(ei, rp, cnt, colx);

    // layer 1 (commuted: aggregate x, then per-head GEMM)
    k_xh<<<xb, 256, 0, stream>>>(x, x16);
    k_avec<<<1, 128, 0, stream>>>(W1, a1s, a1d, pv);
    k_att1<<<tb, 256, 0, stream>>>(x, pv, als, ald);
    k_aggx<<<ab, 256, 0, stream>>>(rp, colx, x16, als, ald, xbar);
    k_post1<<<gb, 256, 0, stream>>>(xbar, W1, b1, pa, bufB);
    // layer 2
    k_gemm<<<gb, 256, 0, stream>>>(bufB, W2, a2s, a2d, h16, als, ald);
    k_agg<0><<<ab, 256, 0, stream>>>(rp, colx, h16, als, ald, b2, pa, bufB);
    // layer 3 (head mean)
    k_gemm<<<gb, 256, 0, stream>>>(bufB, W3, a3s, a3d, h16, als, ald);
    k_agg<1><<<ab, 256, 0, stream>>>(rp, colx, h16, als, ald, b3, pa, bufB);
    // classifier
    k_cls<<<nb, 256, 0, stream>>>(bufB, Wc, bc, out);
}

// Round 6
// 524.064 us; speedup vs baseline: 1.7215x; 1.2365x over previous
//
#include <hip/hip_runtime.h>
#include <stdint.h>

#define NN 100000
#define NE 1600000
#define ET (NE + NN)
#define HC 128
#define HID 64
#define NCLS 12
#define BSZ 512
#define NBK ((NN + BSZ - 1) / BSZ)      // 196
#define CHUNK 8192
#define NPB ((ET + CHUNK - 1) / CHUNK)  // 208

typedef _Float16 f16;
typedef _Float16 f16x2 __attribute__((ext_vector_type(2)));
typedef _Float16 f16x4 __attribute__((ext_vector_type(4)));
typedef _Float16 f16x8 __attribute__((ext_vector_type(8)));

// ---------- CSR build: bucketed counting sort ----------
__global__ void k_init(int* bucketTotal) {
    int i = threadIdx.x;
    if (i < NBK) bucketTotal[i] = 0;
}

__global__ __launch_bounds__(256) void k_hist(const int* __restrict__ ei, int* __restrict__ bucketTotal) {
    __shared__ int h[NBK];
    int tid = threadIdx.x;
    for (int b = tid; b < NBK; b += 256) h[b] = 0;
    __syncthreads();
    long base = (long)blockIdx.x * CHUNK;
#pragma unroll
    for (int k = 0; k < CHUNK / 256; k++) {
        long i = base + k * 256 + tid;
        if (i < ET) {
            int d = (i < NE) ? ei[NE + i] : (int)(i - NE);
            atomicAdd(&h[d >> 9], 1);
        }
    }
    __syncthreads();
    for (int b = tid; b < NBK; b += 256)
        if (h[b]) atomicAdd(&bucketTotal[b], h[b]);
}

__global__ __launch_bounds__(256) void k_bscan(const int* __restrict__ bucketTotal,
                                               int* __restrict__ bucketStart,
                                               int* __restrict__ bucketFill,
                                               int* __restrict__ rp) {
    __shared__ int s[256];
    int tid = threadIdx.x;
    int v = (tid < NBK) ? bucketTotal[tid] : 0;
    s[tid] = v;
    __syncthreads();
    for (int o = 1; o < 256; o <<= 1) {
        int t = (tid >= o) ? s[tid - o] : 0;
        __syncthreads();
        s[tid] += t;
        __syncthreads();
    }
    if (tid < NBK) {
        int excl = s[tid] - v;
        bucketStart[tid] = excl;
        bucketFill[tid] = excl;
    }
    if (tid == 0) { bucketStart[NBK] = ET; rp[NN] = ET; }
}

__global__ __launch_bounds__(256) void k_part(const int* __restrict__ ei,
                                              int* __restrict__ bucketFill,
                                              uint32_t* __restrict__ ebuf) {
    __shared__ int h[NBK];
    __shared__ int base[NBK];
    int tid = threadIdx.x;
    for (int b = tid; b < NBK; b += 256) h[b] = 0;
    __syncthreads();
    long cbase = (long)blockIdx.x * CHUNK;
#pragma unroll
    for (int k = 0; k < CHUNK / 256; k++) {
        long i = cbase + k * 256 + tid;
        if (i < ET) {
            int d = (i < NE) ? ei[NE + i] : (int)(i - NE);
            atomicAdd(&h[d >> 9], 1);
        }
    }
    __syncthreads();
    for (int b = tid; b < NBK; b += 256)
        base[b] = h[b] ? atomicAdd(&bucketFill[b], h[b]) : 0;
    __syncthreads();
    for (int b = tid; b < NBK; b += 256) h[b] = 0;
    __syncthreads();
#pragma unroll
    for (int k = 0; k < CHUNK / 256; k++) {
        long i = cbase + k * 256 + tid;
        if (i < ET) {
            int s, d;
            if (i < NE) { s = ei[i]; d = ei[NE + i]; } else { s = d = (int)(i - NE); }
            int bk = d >> 9;
            int off = atomicAdd(&h[bk], 1);
            ebuf[base[bk] + off] = (uint32_t)s | ((uint32_t)(d & 511) << 17);
        }
    }
}

__global__ __launch_bounds__(512) void k_build(const uint32_t* __restrict__ ebuf,
                                               const int* __restrict__ bucketStart,
                                               int* __restrict__ rp, int* __restrict__ colx) {
    __shared__ int cnt[BSZ];
    __shared__ int fill[BSZ];
    int b = blockIdx.x, tid = threadIdx.x;
    int e0 = bucketStart[b], e1 = bucketStart[b + 1], m = e1 - e0;
    cnt[tid] = 0;
    __syncthreads();
    for (int k = tid; k < m; k += 512) atomicAdd(&cnt[ebuf[e0 + k] >> 17], 1);
    __syncthreads();
    int v = cnt[tid];
    __syncthreads();
    cnt[tid] = v;
    __syncthreads();
    for (int o = 1; o < 512; o <<= 1) {
        int t = (tid >= o) ? cnt[tid - o] : 0;
        __syncthreads();
        cnt[tid] += t;
        __syncthreads();
    }
    int excl = cnt[tid] - v;
    int node = b * BSZ + tid;
    if (node < NN) rp[node] = e0 + excl;
    fill[tid] = e0 + excl;
    __syncthreads();
    for (int k = tid; k < m; k += 512) {
        uint32_t e = ebuf[e0 + k];
        int pos = atomicAdd(&fill[e >> 17], 1);
        colx[pos] = (int)(e & 0x1FFFF);
    }
}

// ---------- layer-1 logits + x16 convert + pv compute (fused) ----------
__global__ __launch_bounds__(256) void k_att1(const float* __restrict__ x,
                                              const float* __restrict__ W1,
                                              const float* __restrict__ a1s,
                                              const float* __restrict__ a1d,
                                              f16* __restrict__ x16,
                                              float* __restrict__ als, float* __restrict__ ald) {
    __shared__ float sIn[128 * 33];
    __shared__ float spv[128];
    int t = threadIdx.x;
    long n0 = (long)blockIdx.x * 128;
    if (t < 128) {  // pv[sd][h][32] computed redundantly per block (cheap, L2-hot)
        int sd = t >> 6, h = (t >> 5) & 1, f = t & 31;
        const float* a = sd ? a1d : a1s;
        float acc = 0.f;
        for (int c = 0; c < 64; c++) acc = fmaf(W1[f * HC + h * 64 + c], a[h * 64 + c], acc);
        spv[t] = acc;
    }
    for (int c = t; c < 128 * 8; c += 256) {
        int row = c >> 3, col = (c & 7) * 4;
        long gn = n0 + row;
        if (gn < NN) {
            float4 v = *(const float4*)(x + gn * 32 + col);
            float* dst = &sIn[row * 33 + col];
            dst[0] = v.x; dst[1] = v.y; dst[2] = v.z; dst[3] = v.w;
            f16x4 o;
            o[0] = (f16)v.x; o[1] = (f16)v.y; o[2] = (f16)v.z; o[3] = (f16)v.w;
            *(f16x4*)(x16 + gn * 32 + col) = o;
        }
    }
    __syncthreads();
    int n = t >> 1, h = t & 1;
    long gn = n0 + n;
    if (gn >= NN) return;
    const float* row = &sIn[n * 33];
    const float* as_ = &spv[h * 32];
    const float* ad_ = &spv[64 + h * 32];
    float s_ = 0.f, d_ = 0.f;
#pragma unroll
    for (int f = 0; f < 32; f++) {
        float v = row[f];
        s_ = fmaf(v, as_[f], s_);
        d_ = fmaf(v, ad_[f], d_);
    }
    als[2 * gn + h] = s_;
    ald[2 * gn + h] = d_;
}

// ---------- layer-1 aggregation: 16 edges/iter, 4 lanes/edge, out xbar[N][2][32] ----------
__global__ __launch_bounds__(256) void k_aggx(const int* __restrict__ rp, const int* __restrict__ colx,
                                              const f16* __restrict__ x16,
                                              const float* __restrict__ als, const float* __restrict__ ald,
                                              float* __restrict__ xbar) {
    int wid = blockIdx.x * 4 + (threadIdx.x >> 6);
    int lane = threadIdx.x & 63;
    int g = lane >> 2, li = lane & 3;          // 16 edge-groups x 4 lanes
    int start = rp[wid], end = rp[wid + 1];
    float2 adv = *(const float2*)(ald + 2 * wid);
    float a0[8], a1[8];
#pragma unroll
    for (int k = 0; k < 8; k++) { a0[k] = 0.f; a1[k] = 0.f; }
    float ws0 = 0.f, ws1 = 0.f;
#pragma unroll 2
    for (int j0 = start; j0 < end; j0 += 16) {
        int j = j0 + g;
        int jc = j < end ? j : end - 1;
        int s = colx[jc];
        float2 asv = *(const float2*)(als + 2 * s);
        float e0 = asv.x + adv.x, e1 = asv.y + adv.y;
        e0 = fmaxf(e0, 0.2f * e0);
        e1 = fmaxf(e1, 0.2f * e1);
        float w0 = __expf(e0), w1 = __expf(e1);
        if (j >= end) { w0 = 0.f; w1 = 0.f; }
        ws0 += w0; ws1 += w1;
        f16x8 xv = *(const f16x8*)(x16 + (long)s * 32 + li * 8);
#pragma unroll
        for (int k = 0; k < 8; k++) {
            float f = (float)xv[k];
            a0[k] = fmaf(w0, f, a0[k]);
            a1[k] = fmaf(w1, f, a1[k]);
        }
    }
#pragma unroll
    for (int o = 4; o <= 32; o <<= 1) {
        ws0 += __shfl_xor(ws0, o);
        ws1 += __shfl_xor(ws1, o);
#pragma unroll
        for (int k = 0; k < 8; k++) {
            a0[k] += __shfl_xor(a0[k], o);
            a1[k] += __shfl_xor(a1[k], o);
        }
    }
    float inv0 = 1.0f / ws0, inv1 = 1.0f / ws1;
    int head = g >> 3, q = g & 7;
    float val = head ? a1[q] * inv1 : a0[q] * inv0;
    xbar[(long)wid * 64 + head * 32 + li * 8 + q] = val;
}

// ---------- layer-1 post GEMM (block-diag K=32/head) + bias + prelu ----------
__global__ __launch_bounds__(256) void k_post1(const float* __restrict__ xb,
                                               const float* __restrict__ W1,
                                               const float* __restrict__ b1,
                                               const float* __restrict__ pap,
                                               float* __restrict__ outp) {
    __shared__ __align__(16) float sIn[64 * 64];
    __shared__ __align__(16) float sW[32 * HC];
    __shared__ float sB[HC];
    int tid = threadIdx.x;
    long n0 = (long)blockIdx.x * 64;
    for (int c = tid; c < 64 * 16; c += 256) {
        int row = c >> 4, col = (c & 15) * 4;
        long gn = n0 + row;
        float4 v = make_float4(0.f, 0.f, 0.f, 0.f);
        if (gn < NN) v = *(const float4*)(xb + gn * 64 + col);
        *(float4*)(sIn + row * 64 + col) = v;
    }
    for (int c = tid; c < 32 * HC / 4; c += 256) ((float4*)sW)[c] = ((const float4*)W1)[c];
    if (tid < HC) sB[tid] = b1[tid];
    __syncthreads();
    int cg = tid & 31, ng = tid >> 5, head = cg >> 4;
    float4 acc[8];
#pragma unroll
    for (int i = 0; i < 8; i++) acc[i] = make_float4(0.f, 0.f, 0.f, 0.f);
    for (int k = 0; k < 32; k++) {
        float4 w = *(const float4*)(sW + k * HC + cg * 4);
#pragma unroll
        for (int i = 0; i < 8; i++) {
            float a = sIn[(ng * 8 + i) * 64 + head * 32 + k];
            acc[i].x = fmaf(a, w.x, acc[i].x);
            acc[i].y = fmaf(a, w.y, acc[i].y);
            acc[i].z = fmaf(a, w.z, acc[i].z);
            acc[i].w = fmaf(a, w.w, acc[i].w);
        }
    }
    float pa = pap[0];
    float4 b = *(const float4*)(sB + cg * 4);
#pragma unroll
    for (int i = 0; i < 8; i++) {
        long n = n0 + ng * 8 + i;
        if (n < NN) {
            float4 o;
            o.x = acc[i].x + b.x; o.y = acc[i].y + b.y;
            o.z = acc[i].z + b.z; o.w = acc[i].w + b.w;
            o.x = o.x >= 0.f ? o.x : pa * o.x;
            o.y = o.y >= 0.f ? o.y : pa * o.y;
            o.z = o.z >= 0.f ? o.z : pa * o.z;
            o.w = o.w >= 0.f ? o.w : pa * o.w;
            *(float4*)(outp + n * HC + cg * 4) = o;
        }
    }
}

// ---------- GEMM h16 = in @ W (K=128) + fused attention projections ----------
__global__ __launch_bounds__(256) void k_gemm(const float* __restrict__ xg,
                                              const float* __restrict__ Wg,
                                              const float* __restrict__ avs,
                                              const float* __restrict__ avd,
                                              f16* __restrict__ h16,
                                              float* __restrict__ als, float* __restrict__ ald) {
    constexpr int K = 128, KT = 64;
    __shared__ __align__(16) float sIn[64 * KT];
    __shared__ __align__(16) float sW[KT * HC];
    __shared__ float sas[HC], sad[HC];
    int tid = threadIdx.x;
    long n0 = (long)blockIdx.x * 64;
    if (tid < HC) { sas[tid] = avs[tid]; sad[tid] = avd[tid]; }
    int cg = tid & 31, ng = tid >> 5;
    float4 acc[8];
#pragma unroll
    for (int i = 0; i < 8; i++) acc[i] = make_float4(0.f, 0.f, 0.f, 0.f);

    for (int kt = 0; kt < K; kt += KT) {
        __syncthreads();
        const float4* wsrc = (const float4*)(Wg + (long)kt * HC);
        for (int c = tid; c < KT * HC / 4; c += 256) ((float4*)sW)[c] = wsrc[c];
        for (int c = tid; c < 64 * KT / 4; c += 256) {
            int row = c / (KT / 4), kc = c % (KT / 4);
            long gn = n0 + row;
            float4 v = make_float4(0.f, 0.f, 0.f, 0.f);
            if (gn < NN) v = *(const float4*)(xg + gn * K + kt + kc * 4);
            *(float4*)(sIn + row * KT + kc * 4) = v;
        }
        __syncthreads();
        for (int k = 0; k < KT; k += 4) {
            float4 w0 = *(const float4*)(sW + (k + 0) * HC + cg * 4);
            float4 w1 = *(const float4*)(sW + (k + 1) * HC + cg * 4);
            float4 w2 = *(const float4*)(sW + (k + 2) * HC + cg * 4);
            float4 w3 = *(const float4*)(sW + (k + 3) * HC + cg * 4);
#pragma unroll
            for (int i = 0; i < 8; i++) {
                float4 a = *(const float4*)(sIn + (ng * 8 + i) * KT + k);
                acc[i].x = fmaf(a.x, w0.x, acc[i].x); acc[i].y = fmaf(a.x, w0.y, acc[i].y);
                acc[i].z = fmaf(a.x, w0.z, acc[i].z); acc[i].w = fmaf(a.x, w0.w, acc[i].w);
                acc[i].x = fmaf(a.y, w1.x, acc[i].x); acc[i].y = fmaf(a.y, w1.y, acc[i].y);
                acc[i].z = fmaf(a.y, w1.z, acc[i].z); acc[i].w = fmaf(a.y, w1.w, acc[i].w);
                acc[i].x = fmaf(a.z, w2.x, acc[i].x); acc[i].y = fmaf(a.z, w2.y, acc[i].y);
                acc[i].z = fmaf(a.z, w2.z, acc[i].z); acc[i].w = fmaf(a.z, w2.w, acc[i].w);
                acc[i].x = fmaf(a.w, w3.x, acc[i].x); acc[i].y = fmaf(a.w, w3.y, acc[i].y);
                acc[i].z = fmaf(a.w, w3.z, acc[i].z); acc[i].w = fmaf(a.w, w3.w, acc[i].w);
            }
        }
    }
    int head = cg >> 4;
#pragma unroll
    for (int i = 0; i < 8; i++) {
        long n = n0 + ng * 8 + i;
        if (n < NN) {
            f16x4 o;
            o[0] = (f16)acc[i].x; o[1] = (f16)acc[i].y;
            o[2] = (f16)acc[i].z; o[3] = (f16)acc[i].w;
            *(f16x4*)(h16 + n * HC + cg * 4) = o;
        }
        const float* ap = (const float*)&acc[i];
        float s_ = 0.f, d_ = 0.f;
#pragma unroll
        for (int j = 0; j < 4; j++) {
            int c = cg * 4 + j;
            s_ = fmaf(ap[j], sas[c], s_);
            d_ = fmaf(ap[j], sad[c], d_);
        }
#pragma unroll
        for (int o = 8; o; o >>= 1) { s_ += __shfl_xor(s_, o); d_ += __shfl_xor(d_, o); }
        if ((cg & 15) == 0 && n < NN) {
            als[2 * n + head] = s_;
            ald[2 * n + head] = d_;
        }
    }
}

// ---------- aggregation over h16: 4 edges/iter, 16 lanes/edge, single pass ----------
template <int MEAN>
__global__ __launch_bounds__(256) void k_agg(const int* __restrict__ rp, const int* __restrict__ colx,
                                             const f16* __restrict__ h,
                                             const float* __restrict__ als, const float* __restrict__ ald,
                                             const float* __restrict__ bias,
                                             const float* __restrict__ pap,
                                             float* __restrict__ outp) {
    int wid = blockIdx.x * 4 + (threadIdx.x >> 6);
    int lane = threadIdx.x & 63;
    int g = lane >> 4, li = lane & 15;         // 4 edge-groups x 16 lanes
    int start = rp[wid], end = rp[wid + 1];
    float2 adv = *(const float2*)(ald + 2 * wid);
    float acc[8];
#pragma unroll
    for (int k = 0; k < 8; k++) acc[k] = 0.f;
    float ws0 = 0.f, ws1 = 0.f;
    bool head1 = li >= 8;
#pragma unroll 4
    for (int j0 = start; j0 < end; j0 += 4) {
        int j = j0 + g;
        int jc = j < end ? j : end - 1;
        int s = colx[jc];
        float2 asv = *(const float2*)(als + 2 * s);
        float e0 = asv.x + adv.x, e1 = asv.y + adv.y;
        e0 = fmaxf(e0, 0.2f * e0);
        e1 = fmaxf(e1, 0.2f * e1);
        float w0 = __expf(e0), w1 = __expf(e1);
        if (j >= end) { w0 = 0.f; w1 = 0.f; }
        ws0 += w0; ws1 += w1;
        f16x8 hv = *(const f16x8*)(h + (long)s * HC + li * 8);
        float wsel = head1 ? w1 : w0;
#pragma unroll
        for (int k = 0; k < 8; k++) acc[k] = fmaf(wsel, (float)hv[k], acc[k]);
    }
#pragma unroll
    for (int o = 16; o <= 32; o <<= 1) {
        ws0 += __shfl_xor(ws0, o);
        ws1 += __shfl_xor(ws1, o);
#pragma unroll
        for (int k = 0; k < 8; k++) acc[k] += __shfl_xor(acc[k], o);
    }
    float pa = pap[0];
    if (!MEAN) {
        float inv = 1.0f / (head1 ? ws1 : ws0);
        int c = li * 8 + g * 2;
        float2 bu = *(const float2*)(bias + c);
        float o0 = acc[g * 2] * inv + bu.x;
        float o1 = acc[g * 2 + 1] * inv + bu.y;
        o0 = o0 >= 0.f ? o0 : pa * o0;
        o1 = o1 >= 0.f ? o1 : pa * o1;
        *(float2*)(outp + (long)wid * HC + c) = make_float2(o0, o1);
    } else {
        float inv = 1.0f / (head1 ? ws1 : ws0);
        float v0 = acc[g * 2] * inv, v1 = acc[g * 2 + 1] * inv;
        float p0 = __shfl_xor(v0, 8), p1 = __shfl_xor(v1, 8);
        if (!head1) {
            int c = li * 8 + g * 2;
            float2 bu = *(const float2*)(bias + c);
            float o0 = 0.5f * (v0 + p0) + bu.x;
            float o1 = 0.5f * (v1 + p1) + bu.y;
            o0 = o0 >= 0.f ? o0 : pa * o0;
            o1 = o1 >= 0.f ? o1 : pa * o1;
            *(float2*)(outp + (long)wid * HID + c) = make_float2(o0, o1);
        }
    }
}

// ---------- classifier ----------
__global__ __launch_bounds__(256) void k_cls(const float* __restrict__ hin,
                                             const float* __restrict__ Wc,
                                             const float* __restrict__ bcp,
                                             float* __restrict__ outp) {
    __shared__ float sW[HID * NCLS];
    __shared__ float sb[NCLS];
    int tid = threadIdx.x;
    for (int c = tid; c < HID * NCLS; c += 256) sW[c] = Wc[c];
    if (tid < NCLS) sb[tid] = bcp[tid];
    __syncthreads();
    int n = blockIdx.x * 256 + tid;
    if (n >= NN) return;
    float o[NCLS];
#pragma unroll
    for (int k = 0; k < NCLS; k++) o[k] = sb[k];
    const float* row = hin + (long)n * HID;
#pragma unroll 8
    for (int c = 0; c < HID; c++) {
        float v = row[c];
#pragma unroll
        for (int k = 0; k < NCLS; k++) o[k] = fmaf(v, sW[c * NCLS + k], o[k]);
    }
#pragma unroll
    for (int k = 0; k < NCLS; k += 2)
        *(float2*)(outp + (long)n * NCLS + k) = make_float2(o[k], o[k + 1]);
}

extern "C" void kernel_launch(void* const* d_in, const int* in_sizes, int n_in,
                              void* d_out, int out_size, void* d_ws, size_t ws_size,
                              hipStream_t stream) {
    const float* x   = (const float*)d_in[0];
    const int*   ei  = (const int*)d_in[1];
    const float* W1  = (const float*)d_in[2];
    const float* a1s = (const float*)d_in[3];
    const float* a1d = (const float*)d_in[4];
    const float* b1  = (const float*)d_in[5];
    const float* W2  = (const float*)d_in[6];
    const float* a2s = (const float*)d_in[7];
    const float* a2d = (const float*)d_in[8];
    const float* b2  = (const float*)d_in[9];
    const float* W3  = (const float*)d_in[10];
    const float* a3s = (const float*)d_in[11];
    const float* a3d = (const float*)d_in[12];
    const float* b3  = (const float*)d_in[13];
    const float* pa  = (const float*)d_in[14];
    const float* Wc  = (const float*)d_in[15];
    const float* bc  = (const float*)d_in[16];
    float* out = (float*)d_out;

    char* w = (char*)d_ws;
    size_t off = 0;
    auto take = [&](size_t b) { void* p = w + off; off += (b + 255) & ~(size_t)255; return p; };
    int* rp      = (int*)take((size_t)(NN + 1) * 4);
    int* colx    = (int*)take((size_t)ET * 4);
    int* btot    = (int*)take((size_t)NBK * 4);
    int* bstart  = (int*)take((size_t)(NBK + 1) * 4);
    int* bfill   = (int*)take((size_t)NBK * 4);
    float* als   = (float*)take((size_t)NN * 8);
    float* ald   = (float*)take((size_t)NN * 8);
    f16* x16     = (f16*)take((size_t)NN * 32 * 2);
    f16* h16     = (f16*)take((size_t)NN * HC * 2);
    float* xbar  = (float*)take((size_t)NN * 64 * 4);
    float* bufB  = (float*)take((size_t)NN * HC * 4);
    uint32_t* ebuf = (uint32_t*)h16;  // alias: ebuf dead before h16's first write (layer-2 gemm)

    int nb = (NN + 255) / 256;       // 391
    int gb = (NN + 63) / 64;         // 1563
    int ab = NN / 4;                 // 25000
    int tb = (NN + 127) / 128;       // 782

    // CSR build: bucketed counting sort (no global-atomic scatter)
    k_init<<<1, 256, 0, stream>>>(btot);
    k_hist<<<NPB, 256, 0, stream>>>(ei, btot);
    k_bscan<<<1, 256, 0, stream>>>(btot, bstart, bfill, rp);
    k_part<<<NPB, 256, 0, stream>>>(ei, bfill, ebuf);
    k_build<<<NBK, 512, 0, stream>>>(ebuf, bstart, rp, colx);

    // layer 1 (commuted: aggregate x, then per-head GEMM)
    k_att1<<<tb, 256, 0, stream>>>(x, W1, a1s, a1d, x16, als, ald);
    k_aggx<<<ab, 256, 0, stream>>>(rp, colx, x16, als, ald, xbar);
    k_post1<<<gb, 256, 0, stream>>>(xbar, W1, b1, pa, bufB);
    // layer 2
    k_gemm<<<gb, 256, 0, stream>>>(bufB, W2, a2s, a2d, h16, als, ald);
    k_agg<0><<<ab, 256, 0, stream>>>(rp, colx, h16, als, ald, b2, pa, bufB);
    // layer 3 (head mean)
    k_gemm<<<gb, 256, 0, stream>>>(bufB, W3, a3s, a3d, h16, als, ald);
    k_agg<1><<<ab, 256, 0, stream>>>(rp, colx, h16, als, ald, b3, pa, bufB);
    // classifier
    k_cls<<<nb, 256, 0, stream>>>(bufB, Wc, bc, out);
}

// Round 7
// 442.085 us; speedup vs baseline: 2.0408x; 1.1854x over previous
//
#include <hip/hip_runtime.h>
#include <stdint.h>

#define NN 100000
#define NE 1600000
#define ET (NE + NN)
#define HC 128
#define HID 64
#define NCLS 12
#define BSZ 512
#define NBK ((NN + BSZ - 1) / BSZ)      // 196
#define CHUNK 8192
#define NPB ((ET + CHUNK - 1) / CHUNK)  // 208

typedef _Float16 f16;
typedef _Float16 f16x2 __attribute__((ext_vector_type(2)));
typedef _Float16 f16x4 __attribute__((ext_vector_type(4)));
typedef _Float16 f16x8 __attribute__((ext_vector_type(8)));
typedef float f32x4 __attribute__((ext_vector_type(4)));

// ---------- CSR build: bucketed counting sort ----------
__global__ void k_init(int* bucketTotal) {
    int i = threadIdx.x;
    if (i < NBK) bucketTotal[i] = 0;
}

__global__ __launch_bounds__(256) void k_hist(const int* __restrict__ ei, int* __restrict__ bucketTotal) {
    __shared__ int h[NBK];
    int tid = threadIdx.x;
    for (int b = tid; b < NBK; b += 256) h[b] = 0;
    __syncthreads();
    long base = (long)blockIdx.x * CHUNK;
#pragma unroll
    for (int k = 0; k < CHUNK / 256; k++) {
        long i = base + k * 256 + tid;
        if (i < ET) {
            int d = (i < NE) ? ei[NE + i] : (int)(i - NE);
            atomicAdd(&h[d >> 9], 1);
        }
    }
    __syncthreads();
    for (int b = tid; b < NBK; b += 256)
        if (h[b]) atomicAdd(&bucketTotal[b], h[b]);
}

__global__ __launch_bounds__(256) void k_bscan(const int* __restrict__ bucketTotal,
                                               int* __restrict__ bucketStart,
                                               int* __restrict__ bucketFill,
                                               int* __restrict__ rp) {
    __shared__ int s[256];
    int tid = threadIdx.x;
    int v = (tid < NBK) ? bucketTotal[tid] : 0;
    s[tid] = v;
    __syncthreads();
    for (int o = 1; o < 256; o <<= 1) {
        int t = (tid >= o) ? s[tid - o] : 0;
        __syncthreads();
        s[tid] += t;
        __syncthreads();
    }
    if (tid < NBK) {
        int excl = s[tid] - v;
        bucketStart[tid] = excl;
        bucketFill[tid] = excl;
    }
    if (tid == 0) { bucketStart[NBK] = ET; rp[NN] = ET; }
}

__global__ __launch_bounds__(256) void k_part(const int* __restrict__ ei,
                                              int* __restrict__ bucketFill,
                                              uint32_t* __restrict__ ebuf) {
    __shared__ int h[NBK];
    __shared__ int base[NBK];
    int tid = threadIdx.x;
    for (int b = tid; b < NBK; b += 256) h[b] = 0;
    __syncthreads();
    long cbase = (long)blockIdx.x * CHUNK;
#pragma unroll
    for (int k = 0; k < CHUNK / 256; k++) {
        long i = cbase + k * 256 + tid;
        if (i < ET) {
            int d = (i < NE) ? ei[NE + i] : (int)(i - NE);
            atomicAdd(&h[d >> 9], 1);
        }
    }
    __syncthreads();
    for (int b = tid; b < NBK; b += 256)
        base[b] = h[b] ? atomicAdd(&bucketFill[b], h[b]) : 0;
    __syncthreads();
    for (int b = tid; b < NBK; b += 256) h[b] = 0;
    __syncthreads();
#pragma unroll
    for (int k = 0; k < CHUNK / 256; k++) {
        long i = cbase + k * 256 + tid;
        if (i < ET) {
            int s, d;
            if (i < NE) { s = ei[i]; d = ei[NE + i]; } else { s = d = (int)(i - NE); }
            int bk = d >> 9;
            int off = atomicAdd(&h[bk], 1);
            ebuf[base[bk] + off] = (uint32_t)s | ((uint32_t)(d & 511) << 17);
        }
    }
}

__global__ __launch_bounds__(512) void k_build(const uint32_t* __restrict__ ebuf,
                                               const int* __restrict__ bucketStart,
                                               int* __restrict__ rp, int* __restrict__ colx) {
    __shared__ int cnt[BSZ];
    __shared__ int fill[BSZ];
    int b = blockIdx.x, tid = threadIdx.x;
    int e0 = bucketStart[b], e1 = bucketStart[b + 1], m = e1 - e0;
    cnt[tid] = 0;
    __syncthreads();
    for (int k = tid; k < m; k += 512) atomicAdd(&cnt[ebuf[e0 + k] >> 17], 1);
    __syncthreads();
    int v = cnt[tid];
    __syncthreads();
    cnt[tid] = v;
    __syncthreads();
    for (int o = 1; o < 512; o <<= 1) {
        int t = (tid >= o) ? cnt[tid - o] : 0;
        __syncthreads();
        cnt[tid] += t;
        __syncthreads();
    }
    int excl = cnt[tid] - v;
    int node = b * BSZ + tid;
    if (node < NN) rp[node] = e0 + excl;
    fill[tid] = e0 + excl;
    __syncthreads();
    for (int k = tid; k < m; k += 512) {
        uint32_t e = ebuf[e0 + k];
        int pos = atomicAdd(&fill[e >> 17], 1);
        colx[pos] = (int)(e & 0x1FFFF);
    }
}

// ---------- W2/W3 -> MFMA-fragment-order split-f16 (hi + residual lo) ----------
// slot s: kk=s>>9, nt=(s>>6)&7, lane=s&63; B[k][n]: n=nt*16+(lane&15), k=kk*32+(lane>>4)*8+j
__global__ void k_wt(const float* __restrict__ W2, const float* __restrict__ W3,
                     f16* __restrict__ wout) {
    const float* W = blockIdx.x ? W3 : W2;
    f16* hi = wout + (size_t)blockIdx.x * 2 * 2048 * 8;
    f16* lo = hi + 2048 * 8;
    for (int s = threadIdx.x; s < 2048; s += 256) {
        int kk = s >> 9, nt = (s >> 6) & 7, l = s & 63;
        int n = nt * 16 + (l & 15), k0 = kk * 32 + (l >> 4) * 8;
        f16x8 vh, vl;
#pragma unroll
        for (int j = 0; j < 8; j++) {
            float v = W[(long)(k0 + j) * HC + n];
            f16 h = (f16)v;
            vh[j] = h;
            vl[j] = (f16)(v - (float)h);
        }
        *(f16x8*)(hi + (size_t)s * 8) = vh;
        *(f16x8*)(lo + (size_t)s * 8) = vl;
    }
}

// ---------- layer-1 logits + x16 convert + pv compute (fused) ----------
__global__ __launch_bounds__(256) void k_att1(const float* __restrict__ x,
                                              const float* __restrict__ W1,
                                              const float* __restrict__ a1s,
                                              const float* __restrict__ a1d,
                                              f16* __restrict__ x16,
                                              float* __restrict__ als, float* __restrict__ ald) {
    __shared__ float sIn[128 * 33];
    __shared__ float spv[128];
    int t = threadIdx.x;
    long n0 = (long)blockIdx.x * 128;
    if (t < 128) {
        int sd = t >> 6, h = (t >> 5) & 1, f = t & 31;
        const float* a = sd ? a1d : a1s;
        float acc = 0.f;
        for (int c = 0; c < 64; c++) acc = fmaf(W1[f * HC + h * 64 + c], a[h * 64 + c], acc);
        spv[t] = acc;
    }
    for (int c = t; c < 128 * 8; c += 256) {
        int row = c >> 3, col = (c & 7) * 4;
        long gn = n0 + row;
        if (gn < NN) {
            float4 v = *(const float4*)(x + gn * 32 + col);
            float* dst = &sIn[row * 33 + col];
            dst[0] = v.x; dst[1] = v.y; dst[2] = v.z; dst[3] = v.w;
            f16x4 o;
            o[0] = (f16)v.x; o[1] = (f16)v.y; o[2] = (f16)v.z; o[3] = (f16)v.w;
            *(f16x4*)(x16 + gn * 32 + col) = o;
        }
    }
    __syncthreads();
    int n = t >> 1, h = t & 1;
    long gn = n0 + n;
    if (gn >= NN) return;
    const float* row = &sIn[n * 33];
    const float* as_ = &spv[h * 32];
    const float* ad_ = &spv[64 + h * 32];
    float s_ = 0.f, d_ = 0.f;
#pragma unroll
    for (int f = 0; f < 32; f++) {
        float v = row[f];
        s_ = fmaf(v, as_[f], s_);
        d_ = fmaf(v, ad_[f], d_);
    }
    als[2 * gn + h] = s_;
    ald[2 * gn + h] = d_;
}

// ---------- layer-1 aggregation: 4 edge-groups x 16 lanes, f16x2/lane ----------
__global__ __launch_bounds__(256) void k_aggx(const int* __restrict__ rp, const int* __restrict__ colx,
                                              const f16* __restrict__ x16,
                                              const float* __restrict__ als, const float* __restrict__ ald,
                                              float* __restrict__ xbar) {
    int wid = blockIdx.x * 4 + (threadIdx.x >> 6);
    int lane = threadIdx.x & 63;
    int g = lane >> 4, li = lane & 15;
    int start = rp[wid], end = rp[wid + 1];
    float2 adv = *(const float2*)(ald + 2 * wid);
    float a00 = 0.f, a01 = 0.f, a10 = 0.f, a11 = 0.f, ws0 = 0.f, ws1 = 0.f;
#pragma unroll 4
    for (int j0 = start; j0 < end; j0 += 4) {
        int j = j0 + g;
        int jc = j < end ? j : end - 1;
        int s = colx[jc];
        float2 asv = *(const float2*)(als + 2 * s);
        float e0 = asv.x + adv.x, e1 = asv.y + adv.y;
        e0 = fmaxf(e0, 0.2f * e0);
        e1 = fmaxf(e1, 0.2f * e1);
        float w0 = __expf(e0), w1 = __expf(e1);
        if (j >= end) { w0 = 0.f; w1 = 0.f; }
        ws0 += w0; ws1 += w1;
        f16x2 xv = *(const f16x2*)(x16 + (long)s * 32 + li * 2);
        float f0 = (float)xv[0], f1 = (float)xv[1];
        a00 = fmaf(w0, f0, a00); a01 = fmaf(w0, f1, a01);
        a10 = fmaf(w1, f0, a10); a11 = fmaf(w1, f1, a11);
    }
#pragma unroll
    for (int o = 16; o <= 32; o <<= 1) {
        ws0 += __shfl_xor(ws0, o); ws1 += __shfl_xor(ws1, o);
        a00 += __shfl_xor(a00, o); a01 += __shfl_xor(a01, o);
        a10 += __shfl_xor(a10, o); a11 += __shfl_xor(a11, o);
    }
    if (g == 0) {
        float inv = 1.0f / ws0;
        *(float2*)(xbar + (long)wid * 64 + li * 2) = make_float2(a00 * inv, a01 * inv);
    } else if (g == 1) {
        float inv = 1.0f / ws1;
        *(float2*)(xbar + (long)wid * 64 + 32 + li * 2) = make_float2(a10 * inv, a11 * inv);
    }
}

// ---------- layer-1 post GEMM (block-diag K=32/head) + bias + prelu -> f16 ----------
__global__ __launch_bounds__(256) void k_post1(const float* __restrict__ xb,
                                               const float* __restrict__ W1,
                                               const float* __restrict__ b1,
                                               const float* __restrict__ pap,
                                               f16* __restrict__ outp) {
    __shared__ __align__(16) float sIn[64 * 64];
    __shared__ __align__(16) float sW[32 * HC];
    __shared__ float sB[HC];
    int tid = threadIdx.x;
    long n0 = (long)blockIdx.x * 64;
    for (int c = tid; c < 64 * 16; c += 256) {
        int row = c >> 4, col = (c & 15) * 4;
        long gn = n0 + row;
        float4 v = make_float4(0.f, 0.f, 0.f, 0.f);
        if (gn < NN) v = *(const float4*)(xb + gn * 64 + col);
        *(float4*)(sIn + row * 64 + col) = v;
    }
    for (int c = tid; c < 32 * HC / 4; c += 256) ((float4*)sW)[c] = ((const float4*)W1)[c];
    if (tid < HC) sB[tid] = b1[tid];
    __syncthreads();
    int cg = tid & 31, ng = tid >> 5, head = cg >> 4;
    float4 acc[8];
#pragma unroll
    for (int i = 0; i < 8; i++) acc[i] = make_float4(0.f, 0.f, 0.f, 0.f);
    for (int k = 0; k < 32; k++) {
        float4 w = *(const float4*)(sW + k * HC + cg * 4);
#pragma unroll
        for (int i = 0; i < 8; i++) {
            float a = sIn[(ng * 8 + i) * 64 + head * 32 + k];
            acc[i].x = fmaf(a, w.x, acc[i].x);
            acc[i].y = fmaf(a, w.y, acc[i].y);
            acc[i].z = fmaf(a, w.z, acc[i].z);
            acc[i].w = fmaf(a, w.w, acc[i].w);
        }
    }
    float pa = pap[0];
    float4 b = *(const float4*)(sB + cg * 4);
#pragma unroll
    for (int i = 0; i < 8; i++) {
        long n = n0 + ng * 8 + i;
        if (n < NN) {
            float o0 = acc[i].x + b.x, o1 = acc[i].y + b.y;
            float o2 = acc[i].z + b.z, o3 = acc[i].w + b.w;
            o0 = o0 >= 0.f ? o0 : pa * o0;
            o1 = o1 >= 0.f ? o1 : pa * o1;
            o2 = o2 >= 0.f ? o2 : pa * o2;
            o3 = o3 >= 0.f ? o3 : pa * o3;
            f16x4 o; o[0] = (f16)o0; o[1] = (f16)o1; o[2] = (f16)o2; o[3] = (f16)o3;
            *(f16x4*)(outp + n * HC + cg * 4) = o;
        }
    }
}

// ---------- MFMA GEMM: h16 = in16 @ (Whi+Wlo) + fused attention projections ----------
__global__ __launch_bounds__(256) void k_gemmM(const f16* __restrict__ in16,
                                               const f16* __restrict__ wfrag,
                                               const float* __restrict__ avs,
                                               const float* __restrict__ avd,
                                               f16* __restrict__ h16,
                                               float* __restrict__ als, float* __restrict__ ald) {
    const f16* whi = wfrag;
    const f16* wlo = wfrag + 2048 * 8;
    int tid = threadIdx.x;
    int w = tid >> 6, l = tid & 63, q = l >> 4, m = l & 15;
    long n0 = (long)blockIdx.x * 64;
    long rowg = n0 + w * 16 + m;
    bool rok = rowg < NN;
    f32x4 acc[8];
#pragma unroll
    for (int i = 0; i < 8; i++) acc[i] = (f32x4){0.f, 0.f, 0.f, 0.f};
#pragma unroll
    for (int kk = 0; kk < 4; kk++) {
        f16x8 a = {};
        if (rok) a = *(const f16x8*)(in16 + rowg * HC + kk * 32 + q * 8);
#pragma unroll
        for (int nt = 0; nt < 8; nt++) {
            f16x8 bh = *(const f16x8*)(whi + ((kk * 8 + nt) * 64 + l) * 8);
            f16x8 bl = *(const f16x8*)(wlo + ((kk * 8 + nt) * 64 + l) * 8);
            acc[nt] = __builtin_amdgcn_mfma_f32_16x16x32_f16(a, bh, acc[nt], 0, 0, 0);
            acc[nt] = __builtin_amdgcn_mfma_f32_16x16x32_f16(a, bl, acc[nt], 0, 0, 0);
        }
    }
    float as_[8], ad_[8];
#pragma unroll
    for (int nt = 0; nt < 8; nt++) { as_[nt] = avs[nt * 16 + m]; ad_[nt] = avd[nt * 16 + m]; }
#pragma unroll
    for (int r = 0; r < 4; r++) {
        long rg = n0 + w * 16 + q * 4 + r;   // C/D: row = q*4 + r, col = nt*16 + m
        bool ok = rg < NN;
        float s0 = 0.f, s1 = 0.f, d0 = 0.f, d1 = 0.f;
#pragma unroll
        for (int nt = 0; nt < 4; nt++) {
            float v = acc[nt][r];
            s0 = fmaf(v, as_[nt], s0); d0 = fmaf(v, ad_[nt], d0);
        }
#pragma unroll
        for (int nt = 4; nt < 8; nt++) {
            float v = acc[nt][r];
            s1 = fmaf(v, as_[nt], s1); d1 = fmaf(v, ad_[nt], d1);
        }
        if (ok) {
#pragma unroll
            for (int nt = 0; nt < 8; nt++) h16[rg * HC + nt * 16 + m] = (f16)acc[nt][r];
        }
#pragma unroll
        for (int o = 1; o <= 8; o <<= 1) {
            s0 += __shfl_xor(s0, o); s1 += __shfl_xor(s1, o);
            d0 += __shfl_xor(d0, o); d1 += __shfl_xor(d1, o);
        }
        if (ok && m == 0) {
            als[2 * rg] = s0; als[2 * rg + 1] = s1;
            ald[2 * rg] = d0; ald[2 * rg + 1] = d1;
        }
    }
}

// ---------- aggregation over h16: 4 edges/iter, 16 lanes/edge ----------
template <int MEAN>
__global__ __launch_bounds__(256) void k_agg(const int* __restrict__ rp, const int* __restrict__ colx,
                                             const f16* __restrict__ h,
                                             const float* __restrict__ als, const float* __restrict__ ald,
                                             const float* __restrict__ bias,
                                             const float* __restrict__ pap,
                                             f16* __restrict__ out16,
                                             float* __restrict__ outf) {
    int wid = blockIdx.x * 4 + (threadIdx.x >> 6);
    int lane = threadIdx.x & 63;
    int g = lane >> 4, li = lane & 15;
    int start = rp[wid], end = rp[wid + 1];
    float2 adv = *(const float2*)(ald + 2 * wid);
    float acc[8];
#pragma unroll
    for (int k = 0; k < 8; k++) acc[k] = 0.f;
    float ws0 = 0.f, ws1 = 0.f;
    bool head1 = li >= 8;
#pragma unroll 4
    for (int j0 = start; j0 < end; j0 += 4) {
        int j = j0 + g;
        int jc = j < end ? j : end - 1;
        int s = colx[jc];
        float2 asv = *(const float2*)(als + 2 * s);
        float e0 = asv.x + adv.x, e1 = asv.y + adv.y;
        e0 = fmaxf(e0, 0.2f * e0);
        e1 = fmaxf(e1, 0.2f * e1);
        float w0 = __expf(e0), w1 = __expf(e1);
        if (j >= end) { w0 = 0.f; w1 = 0.f; }
        ws0 += w0; ws1 += w1;
        f16x8 hv = *(const f16x8*)(h + (long)s * HC + li * 8);
        float wsel = head1 ? w1 : w0;
#pragma unroll
        for (int k = 0; k < 8; k++) acc[k] = fmaf(wsel, (float)hv[k], acc[k]);
    }
#pragma unroll
    for (int o = 16; o <= 32; o <<= 1) {
        ws0 += __shfl_xor(ws0, o);
        ws1 += __shfl_xor(ws1, o);
#pragma unroll
        for (int k = 0; k < 8; k++) acc[k] += __shfl_xor(acc[k], o);
    }
    float pa = pap[0];
    if (!MEAN) {
        float inv = 1.0f / (head1 ? ws1 : ws0);
        int c = li * 8 + g * 2;
        float2 bu = *(const float2*)(bias + c);
        float o0 = acc[g * 2] * inv + bu.x;
        float o1 = acc[g * 2 + 1] * inv + bu.y;
        o0 = o0 >= 0.f ? o0 : pa * o0;
        o1 = o1 >= 0.f ? o1 : pa * o1;
        f16x2 o; o[0] = (f16)o0; o[1] = (f16)o1;
        *(f16x2*)(out16 + (long)wid * HC + c) = o;
    } else {
        float inv = 1.0f / (head1 ? ws1 : ws0);
        float v0 = acc[g * 2] * inv, v1 = acc[g * 2 + 1] * inv;
        float p0 = __shfl_xor(v0, 8), p1 = __shfl_xor(v1, 8);
        if (!head1) {
            int c = li * 8 + g * 2;
            float2 bu = *(const float2*)(bias + c);
            float o0 = 0.5f * (v0 + p0) + bu.x;
            float o1 = 0.5f * (v1 + p1) + bu.y;
            o0 = o0 >= 0.f ? o0 : pa * o0;
            o1 = o1 >= 0.f ? o1 : pa * o1;
            *(float2*)(outf + (long)wid * HID + c) = make_float2(o0, o1);
        }
    }
}

// ---------- classifier ----------
__global__ __launch_bounds__(256) void k_cls(const float* __restrict__ hin,
                                             const float* __restrict__ Wc,
                                             const float* __restrict__ bcp,
                                             float* __restrict__ outp) {
    __shared__ float sW[HID * NCLS];
    __shared__ float sb[NCLS];
    int tid = threadIdx.x;
    for (int c = tid; c < HID * NCLS; c += 256) sW[c] = Wc[c];
    if (tid < NCLS) sb[tid] = bcp[tid];
    __syncthreads();
    int n = blockIdx.x * 256 + tid;
    if (n >= NN) return;
    float o[NCLS];
#pragma unroll
    for (int k = 0; k < NCLS; k++) o[k] = sb[k];
    const float* row = hin + (long)n * HID;
#pragma unroll 8
    for (int c = 0; c < HID; c++) {
        float v = row[c];
#pragma unroll
        for (int k = 0; k < NCLS; k++) o[k] = fmaf(v, sW[c * NCLS + k], o[k]);
    }
#pragma unroll
    for (int k = 0; k < NCLS; k += 2)
        *(float2*)(outp + (long)n * NCLS + k) = make_float2(o[k], o[k + 1]);
}

extern "C" void kernel_launch(void* const* d_in, const int* in_sizes, int n_in,
                              void* d_out, int out_size, void* d_ws, size_t ws_size,
                              hipStream_t stream) {
    const float* x   = (const float*)d_in[0];
    const int*   ei  = (const int*)d_in[1];
    const float* W1  = (const float*)d_in[2];
    const float* a1s = (const float*)d_in[3];
    const float* a1d = (const float*)d_in[4];
    const float* b1  = (const float*)d_in[5];
    const float* W2  = (const float*)d_in[6];
    const float* a2s = (const float*)d_in[7];
    const float* a2d = (const float*)d_in[8];
    const float* b2  = (const float*)d_in[9];
    const float* W3  = (const float*)d_in[10];
    const float* a3s = (const float*)d_in[11];
    const float* a3d = (const float*)d_in[12];
    const float* b3  = (const float*)d_in[13];
    const float* pa  = (const float*)d_in[14];
    const float* Wc  = (const float*)d_in[15];
    const float* bc  = (const float*)d_in[16];
    float* out = (float*)d_out;

    char* w = (char*)d_ws;
    size_t off = 0;
    auto take = [&](size_t b) { void* p = w + off; off += (b + 255) & ~(size_t)255; return p; };
    int* rp      = (int*)take((size_t)(NN + 1) * 4);
    int* colx    = (int*)take((size_t)ET * 4);
    int* btot    = (int*)take((size_t)NBK * 4);
    int* bstart  = (int*)take((size_t)(NBK + 1) * 4);
    int* bfill   = (int*)take((size_t)NBK * 4);
    float* als   = (float*)take((size_t)NN * 8);
    float* ald   = (float*)take((size_t)NN * 8);
    f16* wfrag   = (f16*)take((size_t)2 * 2 * 2048 * 8 * 2);  // [layer][hi/lo][2048][8]
    f16* x16     = (f16*)take((size_t)NN * 32 * 2);
    f16* h16     = (f16*)take((size_t)NN * HC * 2);
    f16* g16     = (f16*)take((size_t)NN * HC * 2);
    float* xbar  = (float*)take((size_t)NN * 64 * 4);
    float* bufB  = (float*)take((size_t)NN * HID * 4);
    uint32_t* ebuf = (uint32_t*)h16;  // alias: ebuf dead before h16's first write

    int nb = (NN + 255) / 256;
    int gb = (NN + 63) / 64;
    int ab = NN / 4;
    int tb = (NN + 127) / 128;

    // CSR build
    k_init<<<1, 256, 0, stream>>>(btot);
    k_hist<<<NPB, 256, 0, stream>>>(ei, btot);
    k_bscan<<<1, 256, 0, stream>>>(btot, bstart, bfill, rp);
    k_part<<<NPB, 256, 0, stream>>>(ei, bfill, ebuf);
    k_build<<<NBK, 512, 0, stream>>>(ebuf, bstart, rp, colx);
    // W fragment tables
    k_wt<<<2, 256, 0, stream>>>(W2, W3, wfrag);

    // layer 1 (commuted)
    k_att1<<<tb, 256, 0, stream>>>(x, W1, a1s, a1d, x16, als, ald);
    k_aggx<<<ab, 256, 0, stream>>>(rp, colx, x16, als, ald, xbar);
    k_post1<<<gb, 256, 0, stream>>>(xbar, W1, b1, pa, g16);
    // layer 2
    k_gemmM<<<gb, 256, 0, stream>>>(g16, wfrag, a2s, a2d, h16, als, ald);
    k_agg<0><<<ab, 256, 0, stream>>>(rp, colx, h16, als, ald, b2, pa, g16, nullptr);
    // layer 3 (head mean)
    k_gemmM<<<gb, 256, 0, stream>>>(g16, wfrag + (size_t)2 * 2048 * 8, a3s, a3d, h16, als, ald);
    k_agg<1><<<ab, 256, 0, stream>>>(rp, colx, h16, als, ald, b3, pa, nullptr, bufB);
    // classifier
    k_cls<<<nb, 256, 0, stream>>>(bufB, Wc, bc, out);
}